// Round 11
// baseline (460.042 us; speedup 1.0000x reference)
//
#include <hip/hip_runtime.h>
#include <hip/hip_bf16.h>
#include <cstddef>

#define BB 4
#define LL 2048
#define DM 256
#define DN 512
#define EE 1024
#define NS 16
#define RK 16
#define NC2 128         // scan chunks (8 blocks/CU)
#define CL2 (LL / NC2)  // chunk length = 16

typedef __attribute__((ext_vector_type(8))) short bf16x8;
typedef __attribute__((ext_vector_type(8))) unsigned short ushort8;
typedef __attribute__((ext_vector_type(4))) unsigned short ushort4v;
typedef __attribute__((ext_vector_type(4))) float f32x4;

__device__ __forceinline__ float fsilu(float x) { return x / (1.0f + __expf(-x)); }
__device__ __forceinline__ float fsoftplus(float x) { return x > 20.0f ? x : log1pf(__expf(x)); }
__device__ __forceinline__ unsigned short f2bf(float x) {  // RNE float->bf16
  union { float f; unsigned int u; } v; v.f = x;
  unsigned int r = v.u + 0x7fffu + ((v.u >> 16) & 1u);
  return (unsigned short)(r >> 16);
}

// ---------------------------------------------------------------------------
// in_proj via bf16 MFMA. Block: 128e x 128l, 4 waves (2x2), wave 64x64 =
// 4x4 MFMA 16x16x32. x-blocks (e<DN): C[e][l] -> xz[b][e][l].
// z-blocks: swap A/B so C[l][d] -> z_t[b][l][d] = silu (coalesced).
// ---------------------------------------------------------------------------
__global__ __launch_bounds__(256) void in_proj_mfma(
    const float* __restrict__ h, const float* __restrict__ w,
    float* __restrict__ xz, float* __restrict__ z_t) {
  __shared__ unsigned short ht[128][40];  // [l][k] bf16, 80B row (16B aligned)
  __shared__ unsigned short wt[128][40];  // [e][k]
  const int b = blockIdx.z;
  const int e0 = blockIdx.y * 128;
  const int l0 = blockIdx.x * 128;
  const int tid = threadIdx.x;
  const int lane = tid & 63;
  const int wid = tid >> 6;
  const int wm = wid >> 1, wn = wid & 1;
  const bool zblk = (e0 >= DN);
  const int krow = (lane >> 4) * 8;
  const int rlo = lane & 15;

  f32x4 acc[4][4];
#pragma unroll
  for (int i = 0; i < 4; i++)
#pragma unroll
    for (int j = 0; j < 4; j++) acc[i][j] = (f32x4){0.f, 0.f, 0.f, 0.f};

  for (int dk = 0; dk < DM; dk += 32) {
#pragma unroll
    for (int it = 0; it < 2; it++) {
      int idx = it * 256 + tid;
      int row = idx >> 2;
      int seg = (idx & 3) * 8;
      const float* hp = h + ((size_t)b * LL + l0 + row) * DM + dk + seg;
      float4 ha = *(const float4*)hp, hb = *(const float4*)(hp + 4);
      ushort8 hv;
      hv[0] = f2bf(ha.x); hv[1] = f2bf(ha.y); hv[2] = f2bf(ha.z); hv[3] = f2bf(ha.w);
      hv[4] = f2bf(hb.x); hv[5] = f2bf(hb.y); hv[6] = f2bf(hb.z); hv[7] = f2bf(hb.w);
      *(ushort8*)&ht[row][seg] = hv;
      const float* wp = w + (size_t)(e0 + row) * DM + dk + seg;
      float4 wa = *(const float4*)wp, wb = *(const float4*)(wp + 4);
      ushort8 wv;
      wv[0] = f2bf(wa.x); wv[1] = f2bf(wa.y); wv[2] = f2bf(wa.z); wv[3] = f2bf(wa.w);
      wv[4] = f2bf(wb.x); wv[5] = f2bf(wb.y); wv[6] = f2bf(wb.z); wv[7] = f2bf(wb.w);
      *(ushort8*)&wt[row][seg] = wv;
    }
    __syncthreads();
    unsigned short (*Ab)[40] = zblk ? ht : wt;
    unsigned short (*Bb)[40] = zblk ? wt : ht;
    bf16x8 af[4], bfr[4];
#pragma unroll
    for (int mt = 0; mt < 4; mt++)
      af[mt] = *(bf16x8*)&Ab[wm * 64 + mt * 16 + rlo][krow];
#pragma unroll
    for (int nt = 0; nt < 4; nt++)
      bfr[nt] = *(bf16x8*)&Bb[wn * 64 + nt * 16 + rlo][krow];
#pragma unroll
    for (int mt = 0; mt < 4; mt++)
#pragma unroll
      for (int nt = 0; nt < 4; nt++)
        acc[mt][nt] = __builtin_amdgcn_mfma_f32_16x16x32_bf16(
            af[mt], bfr[nt], acc[mt][nt], 0, 0, 0);
    __syncthreads();
  }
  if (!zblk) {
#pragma unroll
    for (int mt = 0; mt < 4; mt++)
#pragma unroll
      for (int nt = 0; nt < 4; nt++)
#pragma unroll
        for (int r = 0; r < 4; r++) {
          int e = e0 + wm * 64 + mt * 16 + (lane >> 4) * 4 + r;
          int l = l0 + wn * 64 + nt * 16 + rlo;
          xz[((size_t)b * DN + e) * LL + l] = acc[mt][nt][r];
        }
  } else {
#pragma unroll
    for (int mt = 0; mt < 4; mt++)
#pragma unroll
      for (int nt = 0; nt < 4; nt++)
#pragma unroll
        for (int r = 0; r < 4; r++) {
          int l = l0 + wm * 64 + mt * 16 + (lane >> 4) * 4 + r;
          int d = (e0 - DN) + wn * 64 + nt * 16 + rlo;
          z_t[((size_t)b * LL + l) * DN + d] = fsilu(acc[mt][nt][r]);
        }
  }
}

// ---------------------------------------------------------------------------
// conv_kernel: pure streaming conv+silu+transpose. Block = (128 d-chunk, 32 l).
// ---------------------------------------------------------------------------
__global__ __launch_bounds__(256) void conv_kernel(
    const float* __restrict__ xz,
    const float* __restrict__ cw_f, const float* __restrict__ cb_f,
    const float* __restrict__ cw_r, const float* __restrict__ cb_r,
    float* __restrict__ u_f, float* __restrict__ u_r) {
  __shared__ float xt[128][33];
  const int rev = blockIdx.z;
  const int b = blockIdx.y;
  const int dc0 = (blockIdx.x & 3) * 128;
  const int l0 = (blockIdx.x >> 2) * 32;
  const int tid = threadIdx.x;
  const int lc = tid & 31;
  const int dg = tid >> 5;  // 0..7
  const int l = l0 + lc;
  const float* conv_w = rev ? cw_r : cw_f;
  const float* conv_b = rev ? cb_r : cb_f;
  float* u_out = rev ? u_r : u_f;

#pragma unroll
  for (int i = 0; i < 16; i++) {
    int dloc = dg * 16 + i;
    int dd = dc0 + dloc;
    const float* base = xz + ((size_t)b * DN + dd) * LL;
    float4 cw4 = *(const float4*)(conv_w + dd * 4);
    float a0 = conv_b[dd];
    if (rev) {
      a0 = fmaf(cw4.w, base[l], a0);
      if (l + 1 < LL) a0 = fmaf(cw4.z, base[l + 1], a0);
      if (l + 2 < LL) a0 = fmaf(cw4.y, base[l + 2], a0);
      if (l + 3 < LL) a0 = fmaf(cw4.x, base[l + 3], a0);
    } else {
      a0 = fmaf(cw4.w, base[l], a0);
      if (l - 1 >= 0) a0 = fmaf(cw4.z, base[l - 1], a0);
      if (l - 2 >= 0) a0 = fmaf(cw4.y, base[l - 2], a0);
      if (l - 3 >= 0) a0 = fmaf(cw4.x, base[l - 3], a0);
    }
    xt[dloc][lc] = fsilu(a0);
  }
  __syncthreads();
#pragma unroll
  for (int j = 0; j < 16; j++) {
    int idx = j * 256 + tid;
    int dd = idx & 127;
    int l2 = idx >> 7;
    u_out[((size_t)b * LL + l0 + l2) * DN + dc0 + dd] = xt[dd][l2];
  }
}

// ---------------------------------------------------------------------------
// prep: convert x_w (48x512 fp32) of both branches to bf16 global.
// ---------------------------------------------------------------------------
__global__ __launch_bounds__(256) void xw_prep_kernel(
    const float* __restrict__ xw_f, const float* __restrict__ xw_r,
    unsigned short* __restrict__ o_f, unsigned short* __restrict__ o_r) {
  int i = blockIdx.x * 256 + threadIdx.x;
  if (i < 48 * 512) {
    o_f[i] = f2bf(xw_f[i]);
    o_r[i] = f2bf(xw_r[i]);
  }
}

// ---------------------------------------------------------------------------
// xdbl_kernel: x_dbl GEMM (48 x 16l x 512) + fused delta. Block = 16 l,
// 4 waves each owning a 128-k chunk (12 MFMA), partials reduced via LDS.
// ---------------------------------------------------------------------------
__global__ __launch_bounds__(256) void xdbl_kernel(
    const float* __restrict__ u_f, const float* __restrict__ u_r,
    const unsigned short* __restrict__ xwb_f,
    const unsigned short* __restrict__ xwb_r,
    const float* __restrict__ dtw_f, const float* __restrict__ dtb_f,
    const float* __restrict__ dtw_r, const float* __restrict__ dtb_r,
    float* __restrict__ dl_f, float* __restrict__ B_f, float* __restrict__ C_f,
    float* __restrict__ dl_r, float* __restrict__ B_r, float* __restrict__ C_r) {
  __shared__ __align__(16) unsigned short ub[4][16][136];  // u tile bf16, per k-chunk
  __shared__ float red[4][48][17];                         // per-wave partials
  __shared__ float dtv[16][17];                            // dt rows
  const int rev = blockIdx.z;
  const int b = blockIdx.y;
  const int l0 = blockIdx.x * 16;
  const int tid = threadIdx.x;
  const int lane = tid & 63;
  const int w = tid >> 6;  // wave = k-chunk 0..3
  const int rlo = lane & 15;
  const int hi4 = lane >> 4;  // 0..3
  const int kseg = hi4 * 8;

  const float* up = (rev ? u_r : u_f) + ((size_t)b * LL + l0) * DN;
  const unsigned short* xwb = rev ? xwb_r : xwb_f;
  const float* dt_w = rev ? dtw_r : dtw_f;
  const float* dt_b = rev ? dtb_r : dtb_f;
  float* dl_out = rev ? dl_r : dl_f;
  float* B_out = rev ? B_r : B_f;
  float* C_out = rev ? C_r : C_f;

  // stage u tile [16 l][512 d] -> bf16 (chunked [4][16][136])
#pragma unroll
  for (int j = 0; j < 8; j++) {
    int idx = j * 256 + tid;  // 0..2047 float4 units
    int l2 = idx >> 7;        // 0..15
    int c4 = idx & 127;       // float4 col
    float4 v = *(const float4*)(up + (size_t)l2 * DN + c4 * 4);
    ushort4v t4;
    t4[0] = f2bf(v.x); t4[1] = f2bf(v.y); t4[2] = f2bf(v.z); t4[3] = f2bf(v.w);
    *(ushort4v*)&ub[c4 >> 5][l2][(c4 & 31) * 4] = t4;
  }
  __syncthreads();

  f32x4 am0 = (f32x4){0.f, 0.f, 0.f, 0.f};
  f32x4 am1 = (f32x4){0.f, 0.f, 0.f, 0.f};
  f32x4 am2 = (f32x4){0.f, 0.f, 0.f, 0.f};
#pragma unroll
  for (int ks = 0; ks < 4; ks++) {
    bf16x8 bfrag = *(bf16x8*)&ub[w][rlo][ks * 32 + kseg];
    const unsigned short* xp = xwb + (size_t)(w * 128 + ks * 32 + kseg);
    bf16x8 a0 = *(const bf16x8*)(xp + (size_t)(0 + rlo) * 512);
    bf16x8 a1 = *(const bf16x8*)(xp + (size_t)(16 + rlo) * 512);
    bf16x8 a2 = *(const bf16x8*)(xp + (size_t)(32 + rlo) * 512);
    am0 = __builtin_amdgcn_mfma_f32_16x16x32_bf16(a0, bfrag, am0, 0, 0, 0);
    am1 = __builtin_amdgcn_mfma_f32_16x16x32_bf16(a1, bfrag, am1, 0, 0, 0);
    am2 = __builtin_amdgcn_mfma_f32_16x16x32_bf16(a2, bfrag, am2, 0, 0, 0);
  }
  // write per-wave partials: out row = mt*16 + hi4*4 + r, col = rlo
  {
    const int rbase = hi4 * 4;
#pragma unroll
    for (int r = 0; r < 4; r++) red[w][0 + rbase + r][rlo] = am0[r];
#pragma unroll
    for (int r = 0; r < 4; r++) red[w][16 + rbase + r][rlo] = am1[r];
#pragma unroll
    for (int r = 0; r < 4; r++) red[w][32 + rbase + r][rlo] = am2[r];
  }
  __syncthreads();
  // reduce across waves + scatter
#pragma unroll
  for (int i = 0; i < 3; i++) {
    int o = i * 256 + tid;  // 0..767
    int row = o >> 4, col = o & 15;
    float s = (red[0][row][col] + red[1][row][col]) +
              (red[2][row][col] + red[3][row][col]);
    if (row < 16)
      dtv[row][col] = s;
    else if (row < 32)
      B_out[((size_t)b * LL + l0 + col) * NS + (row - 16)] = s;
    else
      C_out[((size_t)b * LL + l0 + col) * NS + (row - 32)] = s;
  }
  __syncthreads();
  // delta: thread handles d = tid and tid+256, all 16 l
#pragma unroll
  for (int half = 0; half < 2; half++) {
    int dd = half * 256 + tid;
    const float4* wr = (const float4*)(dt_w + (size_t)dd * RK);
    float4 w0 = wr[0], w1 = wr[1], w2 = wr[2], w3 = wr[3];
    float bias = dt_b[dd];
#pragma unroll
    for (int l2 = 0; l2 < 16; l2++) {
      float a0 = bias;
      a0 = fmaf(w0.x, dtv[0][l2], a0);  a0 = fmaf(w0.y, dtv[1][l2], a0);
      a0 = fmaf(w0.z, dtv[2][l2], a0);  a0 = fmaf(w0.w, dtv[3][l2], a0);
      a0 = fmaf(w1.x, dtv[4][l2], a0);  a0 = fmaf(w1.y, dtv[5][l2], a0);
      a0 = fmaf(w1.z, dtv[6][l2], a0);  a0 = fmaf(w1.w, dtv[7][l2], a0);
      a0 = fmaf(w2.x, dtv[8][l2], a0);  a0 = fmaf(w2.y, dtv[9][l2], a0);
      a0 = fmaf(w2.z, dtv[10][l2], a0); a0 = fmaf(w2.w, dtv[11][l2], a0);
      a0 = fmaf(w3.x, dtv[12][l2], a0); a0 = fmaf(w3.y, dtv[13][l2], a0);
      a0 = fmaf(w3.z, dtv[14][l2], a0); a0 = fmaf(w3.w, dtv[15][l2], a0);
      dl_out[((size_t)b * LL + l0 + l2) * DN + dd] = fsoftplus(a0);
    }
  }
}

// ---------------------------------------------------------------------------
// Scan: lane = channel d, 16 states in registers. u/delta/z_t/y in [b][t][d]
// (all coalesced), B/C [b][t][n] wave-uniform float4, ALL streams prefetched
// one step ahead (named registers). y in place over u. NC2=128 -> 8 blk/CU.
// ---------------------------------------------------------------------------
#define HSTEP(n, Bcomp, Ccomp)                      \
  {                                                 \
    float e_ = __expf(dc * Av[n]);                  \
    h[n] = fmaf(e_, h[n], dlu * (Bcomp));           \
    if (PHASE == 3) acc = fmaf(h[n], (Ccomp), acc); \
  }

template <int PHASE>
__global__ __launch_bounds__(256) void scan_kernel(
    float* __restrict__ uy_f, float* __restrict__ uy_r,
    const float* __restrict__ dl_f, const float* __restrict__ dl_r,
    const float* __restrict__ z_t, const float* __restrict__ B_f,
    const float* __restrict__ C_f, const float* __restrict__ B_r,
    const float* __restrict__ C_r, const float* __restrict__ A_log,
    const float* __restrict__ Ab_log, const float* __restrict__ D_f,
    const float* __restrict__ D_r, float* __restrict__ hend,
    float* __restrict__ sumdl) {
  const int G2 = 2 * BB * DN;                            // 4096
  const int ch = (blockIdx.x & 15) * 256 + threadIdx.x;  // channel
  const int chunk = blockIdx.x >> 4;                     // 0..NC2-1
  const bool rev = ch >= BB * DN;                        // uniform per block
  const int cid = rev ? ch - BB * DN : ch;
  const int b = cid >> 9;
  const int d = cid & (DN - 1);

  const float* Arow = (rev ? Ab_log : A_log) + d * NS;
  float Av[NS];
#pragma unroll
  for (int n = 0; n < NS; n++) Av[n] = -__expf(Arow[n]);
  const float Dd = (rev ? D_r : D_f)[d];

  float* uy = (rev ? uy_r : uy_f) + (size_t)b * LL * DN + d;
  const float* dlp = (rev ? dl_r : dl_f) + (size_t)b * LL * DN + d;
  const float* Bp = (rev ? B_r : B_f) + (size_t)b * LL * NS;
  const float* Cp = (rev ? C_r : C_f) + (size_t)b * LL * NS;
  const float* zp = z_t + (size_t)b * LL * DN + d;

  float h[NS];
  if (PHASE == 3) {
    const float* hp = hend + ((size_t)chunk * G2 + ch) * NS;
#pragma unroll
    for (int n = 0; n < NS; n++) h[n] = hp[n];
  } else {
#pragma unroll
    for (int n = 0; n < NS; n++) h[n] = 0.f;
  }

  const int tstep = rev ? -1 : 1;
  int t = rev ? (LL - 1 - CL2 * chunk) : (CL2 * chunk);
  float sdl = 0.f;
  float uc = uy[(size_t)t * DN];
  float dc = dlp[(size_t)t * DN];
  float zc = (PHASE == 3) ? zp[(size_t)t * DN] : 0.f;
  const float4* Bt4 = (const float4*)(Bp + (size_t)t * NS);
  float4 cB0 = Bt4[0], cB1 = Bt4[1], cB2 = Bt4[2], cB3 = Bt4[3];
  float4 cC0 = {0, 0, 0, 0}, cC1 = {0, 0, 0, 0}, cC2 = {0, 0, 0, 0},
         cC3 = {0, 0, 0, 0};
  if (PHASE == 3) {
    const float4* Ct4 = (const float4*)(Cp + (size_t)t * NS);
    cC0 = Ct4[0]; cC1 = Ct4[1]; cC2 = Ct4[2]; cC3 = Ct4[3];
  }

  for (int s = 0; s < CL2; s++) {
    // prefetch step t+1 (clamped; junk discarded after last step)
    int tn = t + tstep;
    int tcl = tn < 0 ? 0 : (tn >= LL ? LL - 1 : tn);
    float un = uy[(size_t)tcl * DN];
    float dn_ = dlp[(size_t)tcl * DN];
    float zn = (PHASE == 3) ? zp[(size_t)tcl * DN] : 0.f;
    const float4* Bn4 = (const float4*)(Bp + (size_t)tcl * NS);
    float4 nB0 = Bn4[0], nB1 = Bn4[1], nB2 = Bn4[2], nB3 = Bn4[3];
    float4 nC0 = {0, 0, 0, 0}, nC1 = {0, 0, 0, 0}, nC2 = {0, 0, 0, 0},
           nC3 = {0, 0, 0, 0};
    if (PHASE == 3) {
      const float4* Cn4 = (const float4*)(Cp + (size_t)tcl * NS);
      nC0 = Cn4[0]; nC1 = Cn4[1]; nC2 = Cn4[2]; nC3 = Cn4[3];
    }
    const float dlu = dc * uc;
    float acc = 0.f;
    HSTEP(0, cB0.x, cC0.x)  HSTEP(1, cB0.y, cC0.y)
    HSTEP(2, cB0.z, cC0.z)  HSTEP(3, cB0.w, cC0.w)
    HSTEP(4, cB1.x, cC1.x)  HSTEP(5, cB1.y, cC1.y)
    HSTEP(6, cB1.z, cC1.z)  HSTEP(7, cB1.w, cC1.w)
    HSTEP(8, cB2.x, cC2.x)  HSTEP(9, cB2.y, cC2.y)
    HSTEP(10, cB2.z, cC2.z) HSTEP(11, cB2.w, cC2.w)
    HSTEP(12, cB3.x, cC3.x) HSTEP(13, cB3.y, cC3.y)
    HSTEP(14, cB3.z, cC3.z) HSTEP(15, cB3.w, cC3.w)
    if (PHASE == 1) sdl += dc;
    if (PHASE == 3) {
      float y = fmaf(uc, Dd, acc) * zc;
      uy[(size_t)t * DN] = y;
    }
    t = tn; uc = un; dc = dn_; zc = zn;
    cB0 = nB0; cB1 = nB1; cB2 = nB2; cB3 = nB3;
    if (PHASE == 3) { cC0 = nC0; cC1 = nC1; cC2 = nC2; cC3 = nC3; }
  }
  if (PHASE == 1) {
    float* hp = hend + ((size_t)chunk * G2 + ch) * NS;
#pragma unroll
    for (int n = 0; n < NS; n++) hp[n] = h[n];
    sumdl[(size_t)chunk * G2 + ch] = sdl;
  }
}
#undef HSTEP

// Phase 2 (in-place): hend[c] <- h0[c] = H_{c-1}; H_c = exp(Av*sumdl[c])*H + hend[c]
__global__ __launch_bounds__(256) void scan_combine_kernel(
    const float* __restrict__ A_log, const float* __restrict__ Ab_log,
    float* __restrict__ hend, const float* __restrict__ sumdl) {
  const int G2 = 2 * BB * DN;
  const int gtid = blockIdx.x * 256 + threadIdx.x;
  const int ch = gtid >> 4;
  const int n = gtid & 15;
  const bool rev = ch >= BB * DN;
  const int d = ch & (DN - 1);
  const float Av = -__expf((rev ? Ab_log : A_log)[d * NS + n]);
  float H = 0.f;
  for (int c = 0; c < NC2; c++) {
    size_t idx = ((size_t)c * G2 + ch) * NS + n;
    float tmp = hend[idx];
    hend[idx] = H;
    if (c < NC2 - 1)
      H = fmaf(__expf(Av * sumdl[(size_t)c * G2 + ch]), H, tmp);
  }
}

// ---------------------------------------------------------------------------
// out_proj via bf16 MFMA: C[l][m] = sum_d 0.5*(yf+yr)[b][l][d] * ow[m][d].
// ---------------------------------------------------------------------------
__global__ __launch_bounds__(256) void out_proj_mfma(
    const float* __restrict__ yf, const float* __restrict__ yr,
    const float* __restrict__ ow, float* __restrict__ outp) {
  __shared__ unsigned short yt[64][40];
  __shared__ unsigned short wo[64][40];
  const int b = blockIdx.z;
  const int m0 = blockIdx.y * 64;
  const int l0 = blockIdx.x * 64;
  const int tid = threadIdx.x;
  const int lane = tid & 63;
  const int wid = tid >> 6;
  const int wm = wid >> 1, wn = wid & 1;
  const int krow = (lane >> 4) * 8;
  const int rlo = lane & 15;

  f32x4 acc[2][2];
#pragma unroll
  for (int i = 0; i < 2; i++)
#pragma unroll
    for (int j = 0; j < 2; j++) acc[i][j] = (f32x4){0.f, 0.f, 0.f, 0.f};

  for (int dk = 0; dk < DN; dk += 32) {
    {
      int row = tid >> 2;
      int seg = (tid & 3) * 8;
      const float* ya = yf + ((size_t)b * LL + l0 + row) * DN + dk + seg;
      const float* yb = yr + ((size_t)b * LL + l0 + row) * DN + dk + seg;
      float4 a0 = *(const float4*)ya, a1 = *(const float4*)(ya + 4);
      float4 b0 = *(const float4*)yb, b1 = *(const float4*)(yb + 4);
      ushort8 yv;
      yv[0] = f2bf(0.5f * (a0.x + b0.x)); yv[1] = f2bf(0.5f * (a0.y + b0.y));
      yv[2] = f2bf(0.5f * (a0.z + b0.z)); yv[3] = f2bf(0.5f * (a0.w + b0.w));
      yv[4] = f2bf(0.5f * (a1.x + b1.x)); yv[5] = f2bf(0.5f * (a1.y + b1.y));
      yv[6] = f2bf(0.5f * (a1.z + b1.z)); yv[7] = f2bf(0.5f * (a1.w + b1.w));
      *(ushort8*)&yt[row][seg] = yv;
      const float* wp = ow + (size_t)(m0 + row) * DN + dk + seg;
      float4 w0 = *(const float4*)wp, w1 = *(const float4*)(wp + 4);
      ushort8 wv;
      wv[0] = f2bf(w0.x); wv[1] = f2bf(w0.y); wv[2] = f2bf(w0.z); wv[3] = f2bf(w0.w);
      wv[4] = f2bf(w1.x); wv[5] = f2bf(w1.y); wv[6] = f2bf(w1.z); wv[7] = f2bf(w1.w);
      *(ushort8*)&wo[row][seg] = wv;
    }
    __syncthreads();
    bf16x8 a0 = *(bf16x8*)&yt[wm * 32 + rlo][krow];
    bf16x8 a1 = *(bf16x8*)&yt[wm * 32 + 16 + rlo][krow];
    bf16x8 b0 = *(bf16x8*)&wo[wn * 32 + rlo][krow];
    bf16x8 b1 = *(bf16x8*)&wo[wn * 32 + 16 + rlo][krow];
    acc[0][0] = __builtin_amdgcn_mfma_f32_16x16x32_bf16(a0, b0, acc[0][0], 0, 0, 0);
    acc[0][1] = __builtin_amdgcn_mfma_f32_16x16x32_bf16(a0, b1, acc[0][1], 0, 0, 0);
    acc[1][0] = __builtin_amdgcn_mfma_f32_16x16x32_bf16(a1, b0, acc[1][0], 0, 0, 0);
    acc[1][1] = __builtin_amdgcn_mfma_f32_16x16x32_bf16(a1, b1, acc[1][1], 0, 0, 0);
    __syncthreads();
  }
#pragma unroll
  for (int mt = 0; mt < 2; mt++)
#pragma unroll
    for (int nt = 0; nt < 2; nt++)
#pragma unroll
      for (int r = 0; r < 4; r++) {
        int l = l0 + wm * 32 + mt * 16 + (lane >> 4) * 4 + r;
        int m = m0 + wn * 32 + nt * 16 + rlo;
        outp[((size_t)b * LL + l) * DM + m] = acc[mt][nt][r];
      }
}

// ---------------------------------------------------------------------------
extern "C" void kernel_launch(void* const* d_in, const int* in_sizes, int n_in,
                              void* d_out, int out_size, void* d_ws, size_t ws_size,
                              hipStream_t stream) {
  (void)in_sizes; (void)n_in; (void)out_size; (void)ws_size;
  const float* A_log = (const float*)d_in[2];
  const float* Ab_log = (const float*)d_in[3];

  const size_t SZ = (size_t)BB * LL * DN;  // 4,194,304 floats
  float* ws = (float*)d_ws;
  float* z_t = ws;                 // SZ  silu(z) transposed
  float* u_f = z_t + SZ;           // SZ  (u -> y in place)
  float* u_r = u_f + SZ;           // SZ
  float* dl_f = u_r + SZ;          // SZ
  float* dl_r = dl_f + SZ;         // SZ
  float* B_f = dl_r + SZ;          // BB*LL*NS
  float* C_f = B_f + (size_t)BB * LL * NS;
  float* B_r = C_f + (size_t)BB * LL * NS;
  float* C_r = B_r + (size_t)BB * LL * NS;
  float* sumdl = C_r + (size_t)BB * LL * NS;             // NC2*G2
  unsigned short* xwbf_f = (unsigned short*)(sumdl + (size_t)NC2 * 2 * BB * DN);
  unsigned short* xwbf_r = xwbf_f + 48 * 512;
  float* xz = (float*)(xwbf_r + 48 * 512);  // SZ (x rows; dead after conv)
  float* hend = xz;  // ALIAS: NC2*G2*NS floats = xz region + tail extension
                     // (xz dead after conv_kernel; hend dead before next in_proj)

  for (int s = 0; s < 2; s++) {
    const int p = 4 + s * 14;
    const float* hin = (const float*)d_in[s];
    const float* in_w = (const float*)d_in[p + 0];
    const float* conv_w = (const float*)d_in[p + 1];
    const float* conv_b = (const float*)d_in[p + 2];
    const float* x_w = (const float*)d_in[p + 3];
    const float* dt_w = (const float*)d_in[p + 4];
    const float* dt_b = (const float*)d_in[p + 5];
    const float* Dp = (const float*)d_in[p + 6];
    const float* conv_w_b = (const float*)d_in[p + 7];
    const float* conv_b_b = (const float*)d_in[p + 8];
    const float* x_w_b = (const float*)d_in[p + 9];
    const float* dt_w_b = (const float*)d_in[p + 10];
    const float* dt_b_b = (const float*)d_in[p + 11];
    const float* Dp_b = (const float*)d_in[p + 12];
    const float* out_w = (const float*)d_in[p + 13];
    float* outp = (float*)d_out + (size_t)s * BB * LL * DM;

    hipLaunchKernelGGL(in_proj_mfma, dim3(LL / 128, EE / 128, BB), dim3(256), 0,
                       stream, hin, in_w, xz, z_t);
    hipLaunchKernelGGL(xw_prep_kernel, dim3(96), dim3(256), 0, stream,
                       x_w, x_w_b, xwbf_f, xwbf_r);
    hipLaunchKernelGGL(conv_kernel, dim3((LL / 32) * 4, BB, 2), dim3(256), 0,
                       stream, xz, conv_w, conv_b, conv_w_b, conv_b_b, u_f, u_r);
    hipLaunchKernelGGL(xdbl_kernel, dim3(LL / 16, BB, 2), dim3(256), 0, stream,
                       u_f, u_r, xwbf_f, xwbf_r, dt_w, dt_b, dt_w_b, dt_b_b,
                       dl_f, B_f, C_f, dl_r, B_r, C_r);
    hipLaunchKernelGGL(HIP_KERNEL_NAME(scan_kernel<1>), dim3(NC2 * 16), dim3(256), 0,
                       stream, u_f, u_r, dl_f, dl_r, z_t, B_f, C_f, B_r, C_r, A_log,
                       Ab_log, Dp, Dp_b, hend, sumdl);
    hipLaunchKernelGGL(scan_combine_kernel, dim3(2 * BB * DN * NS / 256), dim3(256),
                       0, stream, A_log, Ab_log, hend, sumdl);
    hipLaunchKernelGGL(HIP_KERNEL_NAME(scan_kernel<3>), dim3(NC2 * 16), dim3(256), 0,
                       stream, u_f, u_r, dl_f, dl_r, z_t, B_f, C_f, B_r, C_r, A_log,
                       Ab_log, Dp, Dp_b, hend, sumdl);
    hipLaunchKernelGGL(out_proj_mfma, dim3(LL / 64, DM / 64, BB), dim3(256), 0,
                       stream, u_f, u_r, out_w, outp);
  }
}

// Round 12
// 413.700 us; speedup vs baseline: 1.1120x; 1.1120x over previous
//
#include <hip/hip_runtime.h>
#include <hip/hip_bf16.h>
#include <cstddef>

#define BB 4
#define LL 2048
#define DM 256
#define DN 512
#define EE 1024
#define NS 16
#define RK 16
#define NC2 128         // scan chunks (8 blocks/CU)
#define CL2 (LL / NC2)  // chunk length = 16

typedef __attribute__((ext_vector_type(8))) short bf16x8;
typedef __attribute__((ext_vector_type(8))) unsigned short ushort8;
typedef __attribute__((ext_vector_type(4))) unsigned short ushort4v;
typedef __attribute__((ext_vector_type(4))) float f32x4;

__device__ __forceinline__ float fsilu(float x) { return x / (1.0f + __expf(-x)); }
__device__ __forceinline__ float fsoftplus(float x) { return x > 20.0f ? x : log1pf(__expf(x)); }
__device__ __forceinline__ unsigned short f2bf(float x) {  // RNE float->bf16
  union { float f; unsigned int u; } v; v.f = x;
  unsigned int r = v.u + 0x7fffu + ((v.u >> 16) & 1u);
  return (unsigned short)(r >> 16);
}

// ---------------------------------------------------------------------------
// in_proj via bf16 MFMA. Block: 128e x 128l, 4 waves (2x2), wave 64x64 =
// 4x4 MFMA 16x16x32. x-blocks (e<DN): C[e][l] -> xz[b][e][l].
// z-blocks: swap A/B so C[l][d] -> z_t[b][l][d] = silu (coalesced).
// ---------------------------------------------------------------------------
__global__ __launch_bounds__(256) void in_proj_mfma(
    const float* __restrict__ h, const float* __restrict__ w,
    float* __restrict__ xz, float* __restrict__ z_t) {
  __shared__ unsigned short ht[128][40];  // [l][k] bf16, 80B row (16B aligned)
  __shared__ unsigned short wt[128][40];  // [e][k]
  const int b = blockIdx.z;
  const int e0 = blockIdx.y * 128;
  const int l0 = blockIdx.x * 128;
  const int tid = threadIdx.x;
  const int lane = tid & 63;
  const int wid = tid >> 6;
  const int wm = wid >> 1, wn = wid & 1;
  const bool zblk = (e0 >= DN);
  const int krow = (lane >> 4) * 8;
  const int rlo = lane & 15;

  f32x4 acc[4][4];
#pragma unroll
  for (int i = 0; i < 4; i++)
#pragma unroll
    for (int j = 0; j < 4; j++) acc[i][j] = (f32x4){0.f, 0.f, 0.f, 0.f};

  for (int dk = 0; dk < DM; dk += 32) {
#pragma unroll
    for (int it = 0; it < 2; it++) {
      int idx = it * 256 + tid;
      int row = idx >> 2;
      int seg = (idx & 3) * 8;
      const float* hp = h + ((size_t)b * LL + l0 + row) * DM + dk + seg;
      float4 ha = *(const float4*)hp, hb = *(const float4*)(hp + 4);
      ushort8 hv;
      hv[0] = f2bf(ha.x); hv[1] = f2bf(ha.y); hv[2] = f2bf(ha.z); hv[3] = f2bf(ha.w);
      hv[4] = f2bf(hb.x); hv[5] = f2bf(hb.y); hv[6] = f2bf(hb.z); hv[7] = f2bf(hb.w);
      *(ushort8*)&ht[row][seg] = hv;
      const float* wp = w + (size_t)(e0 + row) * DM + dk + seg;
      float4 wa = *(const float4*)wp, wb = *(const float4*)(wp + 4);
      ushort8 wv;
      wv[0] = f2bf(wa.x); wv[1] = f2bf(wa.y); wv[2] = f2bf(wa.z); wv[3] = f2bf(wa.w);
      wv[4] = f2bf(wb.x); wv[5] = f2bf(wb.y); wv[6] = f2bf(wb.z); wv[7] = f2bf(wb.w);
      *(ushort8*)&wt[row][seg] = wv;
    }
    __syncthreads();
    unsigned short (*Ab)[40] = zblk ? ht : wt;
    unsigned short (*Bb)[40] = zblk ? wt : ht;
    bf16x8 af[4], bfr[4];
#pragma unroll
    for (int mt = 0; mt < 4; mt++)
      af[mt] = *(bf16x8*)&Ab[wm * 64 + mt * 16 + rlo][krow];
#pragma unroll
    for (int nt = 0; nt < 4; nt++)
      bfr[nt] = *(bf16x8*)&Bb[wn * 64 + nt * 16 + rlo][krow];
#pragma unroll
    for (int mt = 0; mt < 4; mt++)
#pragma unroll
      for (int nt = 0; nt < 4; nt++)
        acc[mt][nt] = __builtin_amdgcn_mfma_f32_16x16x32_bf16(
            af[mt], bfr[nt], acc[mt][nt], 0, 0, 0);
    __syncthreads();
  }
  if (!zblk) {
#pragma unroll
    for (int mt = 0; mt < 4; mt++)
#pragma unroll
      for (int nt = 0; nt < 4; nt++)
#pragma unroll
        for (int r = 0; r < 4; r++) {
          int e = e0 + wm * 64 + mt * 16 + (lane >> 4) * 4 + r;
          int l = l0 + wn * 64 + nt * 16 + rlo;
          xz[((size_t)b * DN + e) * LL + l] = acc[mt][nt][r];
        }
  } else {
#pragma unroll
    for (int mt = 0; mt < 4; mt++)
#pragma unroll
      for (int nt = 0; nt < 4; nt++)
#pragma unroll
        for (int r = 0; r < 4; r++) {
          int l = l0 + wm * 64 + mt * 16 + (lane >> 4) * 4 + r;
          int d = (e0 - DN) + wn * 64 + nt * 16 + rlo;
          z_t[((size_t)b * LL + l) * DN + d] = fsilu(acc[mt][nt][r]);
        }
  }
}

// ---------------------------------------------------------------------------
// conv_kernel: pure streaming conv+silu+transpose. Block = (128 d-chunk, 32 l).
// ---------------------------------------------------------------------------
__global__ __launch_bounds__(256) void conv_kernel(
    const float* __restrict__ xz,
    const float* __restrict__ cw_f, const float* __restrict__ cb_f,
    const float* __restrict__ cw_r, const float* __restrict__ cb_r,
    float* __restrict__ u_f, float* __restrict__ u_r) {
  __shared__ float xt[128][33];
  const int rev = blockIdx.z;
  const int b = blockIdx.y;
  const int dc0 = (blockIdx.x & 3) * 128;
  const int l0 = (blockIdx.x >> 2) * 32;
  const int tid = threadIdx.x;
  const int lc = tid & 31;
  const int dg = tid >> 5;  // 0..7
  const int l = l0 + lc;
  const float* conv_w = rev ? cw_r : cw_f;
  const float* conv_b = rev ? cb_r : cb_f;
  float* u_out = rev ? u_r : u_f;

#pragma unroll
  for (int i = 0; i < 16; i++) {
    int dloc = dg * 16 + i;
    int dd = dc0 + dloc;
    const float* base = xz + ((size_t)b * DN + dd) * LL;
    float4 cw4 = *(const float4*)(conv_w + dd * 4);
    float a0 = conv_b[dd];
    if (rev) {
      a0 = fmaf(cw4.w, base[l], a0);
      if (l + 1 < LL) a0 = fmaf(cw4.z, base[l + 1], a0);
      if (l + 2 < LL) a0 = fmaf(cw4.y, base[l + 2], a0);
      if (l + 3 < LL) a0 = fmaf(cw4.x, base[l + 3], a0);
    } else {
      a0 = fmaf(cw4.w, base[l], a0);
      if (l - 1 >= 0) a0 = fmaf(cw4.z, base[l - 1], a0);
      if (l - 2 >= 0) a0 = fmaf(cw4.y, base[l - 2], a0);
      if (l - 3 >= 0) a0 = fmaf(cw4.x, base[l - 3], a0);
    }
    xt[dloc][lc] = fsilu(a0);
  }
  __syncthreads();
#pragma unroll
  for (int j = 0; j < 16; j++) {
    int idx = j * 256 + tid;
    int dd = idx & 127;
    int l2 = idx >> 7;
    u_out[((size_t)b * LL + l0 + l2) * DN + dc0 + dd] = xt[dd][l2];
  }
}

// ---------------------------------------------------------------------------
// prep: convert x_w (48x512 fp32) of both branches to bf16 global.
// ---------------------------------------------------------------------------
__global__ __launch_bounds__(256) void xw_prep_kernel(
    const float* __restrict__ xw_f, const float* __restrict__ xw_r,
    unsigned short* __restrict__ o_f, unsigned short* __restrict__ o_r) {
  int i = blockIdx.x * 256 + threadIdx.x;
  if (i < 48 * 512) {
    o_f[i] = f2bf(xw_f[i]);
    o_r[i] = f2bf(xw_r[i]);
  }
}

// ---------------------------------------------------------------------------
// xdbl_kernel: x_dbl GEMM (48 x 16l x 512) + fused delta. Block = 16 l,
// 4 waves each owning a 128-k chunk (12 MFMA), partials reduced via LDS.
// ---------------------------------------------------------------------------
__global__ __launch_bounds__(256) void xdbl_kernel(
    const float* __restrict__ u_f, const float* __restrict__ u_r,
    const unsigned short* __restrict__ xwb_f,
    const unsigned short* __restrict__ xwb_r,
    const float* __restrict__ dtw_f, const float* __restrict__ dtb_f,
    const float* __restrict__ dtw_r, const float* __restrict__ dtb_r,
    float* __restrict__ dl_f, float* __restrict__ B_f, float* __restrict__ C_f,
    float* __restrict__ dl_r, float* __restrict__ B_r, float* __restrict__ C_r) {
  __shared__ __align__(16) unsigned short ub[4][16][136];  // u tile bf16, per k-chunk
  __shared__ float red[4][48][17];                         // per-wave partials
  __shared__ float dtv[16][17];                            // dt rows
  const int rev = blockIdx.z;
  const int b = blockIdx.y;
  const int l0 = blockIdx.x * 16;
  const int tid = threadIdx.x;
  const int lane = tid & 63;
  const int w = tid >> 6;  // wave = k-chunk 0..3
  const int rlo = lane & 15;
  const int hi4 = lane >> 4;  // 0..3
  const int kseg = hi4 * 8;

  const float* up = (rev ? u_r : u_f) + ((size_t)b * LL + l0) * DN;
  const unsigned short* xwb = rev ? xwb_r : xwb_f;
  const float* dt_w = rev ? dtw_r : dtw_f;
  const float* dt_b = rev ? dtb_r : dtb_f;
  float* dl_out = rev ? dl_r : dl_f;
  float* B_out = rev ? B_r : B_f;
  float* C_out = rev ? C_r : C_f;

  // stage u tile [16 l][512 d] -> bf16 (chunked [4][16][136])
#pragma unroll
  for (int j = 0; j < 8; j++) {
    int idx = j * 256 + tid;  // 0..2047 float4 units
    int l2 = idx >> 7;        // 0..15
    int c4 = idx & 127;       // float4 col
    float4 v = *(const float4*)(up + (size_t)l2 * DN + c4 * 4);
    ushort4v t4;
    t4[0] = f2bf(v.x); t4[1] = f2bf(v.y); t4[2] = f2bf(v.z); t4[3] = f2bf(v.w);
    *(ushort4v*)&ub[c4 >> 5][l2][(c4 & 31) * 4] = t4;
  }
  __syncthreads();

  f32x4 am0 = (f32x4){0.f, 0.f, 0.f, 0.f};
  f32x4 am1 = (f32x4){0.f, 0.f, 0.f, 0.f};
  f32x4 am2 = (f32x4){0.f, 0.f, 0.f, 0.f};
#pragma unroll
  for (int ks = 0; ks < 4; ks++) {
    bf16x8 bfrag = *(bf16x8*)&ub[w][rlo][ks * 32 + kseg];
    const unsigned short* xp = xwb + (size_t)(w * 128 + ks * 32 + kseg);
    bf16x8 a0 = *(const bf16x8*)(xp + (size_t)(0 + rlo) * 512);
    bf16x8 a1 = *(const bf16x8*)(xp + (size_t)(16 + rlo) * 512);
    bf16x8 a2 = *(const bf16x8*)(xp + (size_t)(32 + rlo) * 512);
    am0 = __builtin_amdgcn_mfma_f32_16x16x32_bf16(a0, bfrag, am0, 0, 0, 0);
    am1 = __builtin_amdgcn_mfma_f32_16x16x32_bf16(a1, bfrag, am1, 0, 0, 0);
    am2 = __builtin_amdgcn_mfma_f32_16x16x32_bf16(a2, bfrag, am2, 0, 0, 0);
  }
  // write per-wave partials: out row = mt*16 + hi4*4 + r, col = rlo
  {
    const int rbase = hi4 * 4;
#pragma unroll
    for (int r = 0; r < 4; r++) red[w][0 + rbase + r][rlo] = am0[r];
#pragma unroll
    for (int r = 0; r < 4; r++) red[w][16 + rbase + r][rlo] = am1[r];
#pragma unroll
    for (int r = 0; r < 4; r++) red[w][32 + rbase + r][rlo] = am2[r];
  }
  __syncthreads();
  // reduce across waves + scatter
#pragma unroll
  for (int i = 0; i < 3; i++) {
    int o = i * 256 + tid;  // 0..767
    int row = o >> 4, col = o & 15;
    float s = (red[0][row][col] + red[1][row][col]) +
              (red[2][row][col] + red[3][row][col]);
    if (row < 16)
      dtv[row][col] = s;
    else if (row < 32)
      B_out[((size_t)b * LL + l0 + col) * NS + (row - 16)] = s;
    else
      C_out[((size_t)b * LL + l0 + col) * NS + (row - 32)] = s;
  }
  __syncthreads();
  // delta: thread handles d = tid and tid+256, all 16 l
#pragma unroll
  for (int half = 0; half < 2; half++) {
    int dd = half * 256 + tid;
    const float4* wr = (const float4*)(dt_w + (size_t)dd * RK);
    float4 w0 = wr[0], w1 = wr[1], w2 = wr[2], w3 = wr[3];
    float bias = dt_b[dd];
#pragma unroll
    for (int l2 = 0; l2 < 16; l2++) {
      float a0 = bias;
      a0 = fmaf(w0.x, dtv[0][l2], a0);  a0 = fmaf(w0.y, dtv[1][l2], a0);
      a0 = fmaf(w0.z, dtv[2][l2], a0);  a0 = fmaf(w0.w, dtv[3][l2], a0);
      a0 = fmaf(w1.x, dtv[4][l2], a0);  a0 = fmaf(w1.y, dtv[5][l2], a0);
      a0 = fmaf(w1.z, dtv[6][l2], a0);  a0 = fmaf(w1.w, dtv[7][l2], a0);
      a0 = fmaf(w2.x, dtv[8][l2], a0);  a0 = fmaf(w2.y, dtv[9][l2], a0);
      a0 = fmaf(w2.z, dtv[10][l2], a0); a0 = fmaf(w2.w, dtv[11][l2], a0);
      a0 = fmaf(w3.x, dtv[12][l2], a0); a0 = fmaf(w3.y, dtv[13][l2], a0);
      a0 = fmaf(w3.z, dtv[14][l2], a0); a0 = fmaf(w3.w, dtv[15][l2], a0);
      dl_out[((size_t)b * LL + l0 + l2) * DN + dd] = fsoftplus(a0);
    }
  }
}

// ---------------------------------------------------------------------------
// Scan: lane = channel d, 16 states in registers. u/delta/z_t/y in [b][t][d]
// (all coalesced), B/C [b][t][n] wave-uniform float4, ALL streams prefetched
// one step ahead (named registers). y in place over u. NC2=128 -> 8 blk/CU.
// ---------------------------------------------------------------------------
#define HSTEP(n, Bcomp, Ccomp)                      \
  {                                                 \
    float e_ = __expf(dc * Av[n]);                  \
    h[n] = fmaf(e_, h[n], dlu * (Bcomp));           \
    if (PHASE == 3) acc = fmaf(h[n], (Ccomp), acc); \
  }

template <int PHASE>
__global__ __launch_bounds__(256) void scan_kernel(
    float* __restrict__ uy_f, float* __restrict__ uy_r,
    const float* __restrict__ dl_f, const float* __restrict__ dl_r,
    const float* __restrict__ z_t, const float* __restrict__ B_f,
    const float* __restrict__ C_f, const float* __restrict__ B_r,
    const float* __restrict__ C_r, const float* __restrict__ A_log,
    const float* __restrict__ Ab_log, const float* __restrict__ D_f,
    const float* __restrict__ D_r, float* __restrict__ hend,
    float* __restrict__ sumdl) {
  const int G2 = 2 * BB * DN;                            // 4096
  const int ch = (blockIdx.x & 15) * 256 + threadIdx.x;  // channel
  const int chunk = blockIdx.x >> 4;                     // 0..NC2-1
  const bool rev = ch >= BB * DN;                        // uniform per block
  const int cid = rev ? ch - BB * DN : ch;
  const int b = cid >> 9;
  const int d = cid & (DN - 1);

  const float* Arow = (rev ? Ab_log : A_log) + d * NS;
  float Av[NS];
#pragma unroll
  for (int n = 0; n < NS; n++) Av[n] = -__expf(Arow[n]);
  const float Dd = (rev ? D_r : D_f)[d];

  float* uy = (rev ? uy_r : uy_f) + (size_t)b * LL * DN + d;
  const float* dlp = (rev ? dl_r : dl_f) + (size_t)b * LL * DN + d;
  const float* Bp = (rev ? B_r : B_f) + (size_t)b * LL * NS;
  const float* Cp = (rev ? C_r : C_f) + (size_t)b * LL * NS;
  const float* zp = z_t + (size_t)b * LL * DN + d;

  float h[NS];
  if (PHASE == 3) {
    const float* hp = hend + ((size_t)chunk * G2 + ch) * NS;
#pragma unroll
    for (int n = 0; n < NS; n++) h[n] = hp[n];
  } else {
#pragma unroll
    for (int n = 0; n < NS; n++) h[n] = 0.f;
  }

  const int tstep = rev ? -1 : 1;
  int t = rev ? (LL - 1 - CL2 * chunk) : (CL2 * chunk);
  float sdl = 0.f;
  float uc = uy[(size_t)t * DN];
  float dc = dlp[(size_t)t * DN];
  float zc = (PHASE == 3) ? zp[(size_t)t * DN] : 0.f;
  const float4* Bt4 = (const float4*)(Bp + (size_t)t * NS);
  float4 cB0 = Bt4[0], cB1 = Bt4[1], cB2 = Bt4[2], cB3 = Bt4[3];
  float4 cC0 = {0, 0, 0, 0}, cC1 = {0, 0, 0, 0}, cC2 = {0, 0, 0, 0},
         cC3 = {0, 0, 0, 0};
  if (PHASE == 3) {
    const float4* Ct4 = (const float4*)(Cp + (size_t)t * NS);
    cC0 = Ct4[0]; cC1 = Ct4[1]; cC2 = Ct4[2]; cC3 = Ct4[3];
  }

  for (int s = 0; s < CL2; s++) {
    // prefetch step t+1 (clamped; junk discarded after last step)
    int tn = t + tstep;
    int tcl = tn < 0 ? 0 : (tn >= LL ? LL - 1 : tn);
    float un = uy[(size_t)tcl * DN];
    float dn_ = dlp[(size_t)tcl * DN];
    float zn = (PHASE == 3) ? zp[(size_t)tcl * DN] : 0.f;
    const float4* Bn4 = (const float4*)(Bp + (size_t)tcl * NS);
    float4 nB0 = Bn4[0], nB1 = Bn4[1], nB2 = Bn4[2], nB3 = Bn4[3];
    float4 nC0 = {0, 0, 0, 0}, nC1 = {0, 0, 0, 0}, nC2 = {0, 0, 0, 0},
           nC3 = {0, 0, 0, 0};
    if (PHASE == 3) {
      const float4* Cn4 = (const float4*)(Cp + (size_t)tcl * NS);
      nC0 = Cn4[0]; nC1 = Cn4[1]; nC2 = Cn4[2]; nC3 = Cn4[3];
    }
    const float dlu = dc * uc;
    float acc = 0.f;
    HSTEP(0, cB0.x, cC0.x)  HSTEP(1, cB0.y, cC0.y)
    HSTEP(2, cB0.z, cC0.z)  HSTEP(3, cB0.w, cC0.w)
    HSTEP(4, cB1.x, cC1.x)  HSTEP(5, cB1.y, cC1.y)
    HSTEP(6, cB1.z, cC1.z)  HSTEP(7, cB1.w, cC1.w)
    HSTEP(8, cB2.x, cC2.x)  HSTEP(9, cB2.y, cC2.y)
    HSTEP(10, cB2.z, cC2.z) HSTEP(11, cB2.w, cC2.w)
    HSTEP(12, cB3.x, cC3.x) HSTEP(13, cB3.y, cC3.y)
    HSTEP(14, cB3.z, cC3.z) HSTEP(15, cB3.w, cC3.w)
    if (PHASE == 1) sdl += dc;
    if (PHASE == 3) {
      float y = fmaf(uc, Dd, acc) * zc;
      uy[(size_t)t * DN] = y;
    }
    t = tn; uc = un; dc = dn_; zc = zn;
    cB0 = nB0; cB1 = nB1; cB2 = nB2; cB3 = nB3;
    if (PHASE == 3) { cC0 = nC0; cC1 = nC1; cC2 = nC2; cC3 = nC3; }
  }
  if (PHASE == 1) {
    float* hp = hend + ((size_t)chunk * G2 + ch) * NS;
#pragma unroll
    for (int n = 0; n < NS; n++) hp[n] = h[n];
    sumdl[(size_t)chunk * G2 + ch] = sdl;
  }
}
#undef HSTEP

// ---------------------------------------------------------------------------
// Phase 2 (in-place, LDS-tiled): block owns 16 channels x 16 states. Per
// 8-chunk tile: batch-load hend slab (8 independent coalesced loads -> all
// in flight), run recurrence from LDS, store h0 back in place. The global
// loads are OFF the dependent chain (old version serialized 128 dependent
// loads against aliasing stores).
// ---------------------------------------------------------------------------
__global__ __launch_bounds__(256) void scan_combine_kernel(
    const float* __restrict__ A_log, const float* __restrict__ Ab_log,
    float* __restrict__ hend, const float* __restrict__ sumdl) {
  const int G2 = 2 * BB * DN;
  __shared__ float tile[8][256];
  __shared__ float sd[8][16];
  const int tid = threadIdx.x;
  const int ch0 = blockIdx.x * 16;
  const int chl = tid >> 4;  // local channel 0..15
  const int n = tid & 15;
  const int ch = ch0 + chl;
  const bool rev = ch >= BB * DN;
  const int d = ch & (DN - 1);
  const float Av = -__expf((rev ? Ab_log : A_log)[d * NS + n]);
  float H = 0.f;
  for (int cb = 0; cb < NC2 / 8; cb++) {
#pragma unroll
    for (int j = 0; j < 8; j++)
      tile[j][tid] = hend[((size_t)(cb * 8 + j) * G2 + ch0) * NS + tid];
    if (tid < 128) {
      int j = tid >> 4, k = tid & 15;
      sd[j][k] = sumdl[(size_t)(cb * 8 + j) * G2 + ch0 + k];
    }
    __syncthreads();
#pragma unroll
    for (int j = 0; j < 8; j++) {
      float tmp = tile[j][tid];
      tile[j][tid] = H;
      H = fmaf(__expf(Av * sd[j][chl]), H, tmp);
    }
    __syncthreads();
#pragma unroll
    for (int j = 0; j < 8; j++)
      hend[((size_t)(cb * 8 + j) * G2 + ch0) * NS + tid] = tile[j][tid];
    __syncthreads();
  }
}

// ---------------------------------------------------------------------------
// out_proj via bf16 MFMA: C[l][m] = sum_d 0.5*(yf+yr)[b][l][d] * ow[m][d].
// ---------------------------------------------------------------------------
__global__ __launch_bounds__(256) void out_proj_mfma(
    const float* __restrict__ yf, const float* __restrict__ yr,
    const float* __restrict__ ow, float* __restrict__ outp) {
  __shared__ unsigned short yt[64][40];
  __shared__ unsigned short wo[64][40];
  const int b = blockIdx.z;
  const int m0 = blockIdx.y * 64;
  const int l0 = blockIdx.x * 64;
  const int tid = threadIdx.x;
  const int lane = tid & 63;
  const int wid = tid >> 6;
  const int wm = wid >> 1, wn = wid & 1;
  const int krow = (lane >> 4) * 8;
  const int rlo = lane & 15;

  f32x4 acc[2][2];
#pragma unroll
  for (int i = 0; i < 2; i++)
#pragma unroll
    for (int j = 0; j < 2; j++) acc[i][j] = (f32x4){0.f, 0.f, 0.f, 0.f};

  for (int dk = 0; dk < DN; dk += 32) {
    {
      int row = tid >> 2;
      int seg = (tid & 3) * 8;
      const float* ya = yf + ((size_t)b * LL + l0 + row) * DN + dk + seg;
      const float* yb = yr + ((size_t)b * LL + l0 + row) * DN + dk + seg;
      float4 a0 = *(const float4*)ya, a1 = *(const float4*)(ya + 4);
      float4 b0 = *(const float4*)yb, b1 = *(const float4*)(yb + 4);
      ushort8 yv;
      yv[0] = f2bf(0.5f * (a0.x + b0.x)); yv[1] = f2bf(0.5f * (a0.y + b0.y));
      yv[2] = f2bf(0.5f * (a0.z + b0.z)); yv[3] = f2bf(0.5f * (a0.w + b0.w));
      yv[4] = f2bf(0.5f * (a1.x + b1.x)); yv[5] = f2bf(0.5f * (a1.y + b1.y));
      yv[6] = f2bf(0.5f * (a1.z + b1.z)); yv[7] = f2bf(0.5f * (a1.w + b1.w));
      *(ushort8*)&yt[row][seg] = yv;
      const float* wp = ow + (size_t)(m0 + row) * DN + dk + seg;
      float4 w0 = *(const float4*)wp, w1 = *(const float4*)(wp + 4);
      ushort8 wv;
      wv[0] = f2bf(w0.x); wv[1] = f2bf(w0.y); wv[2] = f2bf(w0.z); wv[3] = f2bf(w0.w);
      wv[4] = f2bf(w1.x); wv[5] = f2bf(w1.y); wv[6] = f2bf(w1.z); wv[7] = f2bf(w1.w);
      *(ushort8*)&wo[row][seg] = wv;
    }
    __syncthreads();
    bf16x8 a0 = *(bf16x8*)&yt[wm * 32 + rlo][krow];
    bf16x8 a1 = *(bf16x8*)&yt[wm * 32 + 16 + rlo][krow];
    bf16x8 b0 = *(bf16x8*)&wo[wn * 32 + rlo][krow];
    bf16x8 b1 = *(bf16x8*)&wo[wn * 32 + 16 + rlo][krow];
    acc[0][0] = __builtin_amdgcn_mfma_f32_16x16x32_bf16(a0, b0, acc[0][0], 0, 0, 0);
    acc[0][1] = __builtin_amdgcn_mfma_f32_16x16x32_bf16(a0, b1, acc[0][1], 0, 0, 0);
    acc[1][0] = __builtin_amdgcn_mfma_f32_16x16x32_bf16(a1, b0, acc[1][0], 0, 0, 0);
    acc[1][1] = __builtin_amdgcn_mfma_f32_16x16x32_bf16(a1, b1, acc[1][1], 0, 0, 0);
    __syncthreads();
  }
#pragma unroll
  for (int mt = 0; mt < 2; mt++)
#pragma unroll
    for (int nt = 0; nt < 2; nt++)
#pragma unroll
      for (int r = 0; r < 4; r++) {
        int l = l0 + wm * 32 + mt * 16 + (lane >> 4) * 4 + r;
        int m = m0 + wn * 32 + nt * 16 + rlo;
        outp[((size_t)b * LL + l) * DM + m] = acc[mt][nt][r];
      }
}

// ---------------------------------------------------------------------------
extern "C" void kernel_launch(void* const* d_in, const int* in_sizes, int n_in,
                              void* d_out, int out_size, void* d_ws, size_t ws_size,
                              hipStream_t stream) {
  (void)in_sizes; (void)n_in; (void)out_size; (void)ws_size;
  const float* A_log = (const float*)d_in[2];
  const float* Ab_log = (const float*)d_in[3];

  const size_t SZ = (size_t)BB * LL * DN;  // 4,194,304 floats
  float* ws = (float*)d_ws;
  float* z_t = ws;                 // SZ  silu(z) transposed
  float* u_f = z_t + SZ;           // SZ  (u -> y in place)
  float* u_r = u_f + SZ;           // SZ
  float* dl_f = u_r + SZ;          // SZ
  float* dl_r = dl_f + SZ;         // SZ
  float* B_f = dl_r + SZ;          // BB*LL*NS
  float* C_f = B_f + (size_t)BB * LL * NS;
  float* B_r = C_f + (size_t)BB * LL * NS;
  float* C_r = B_r + (size_t)BB * LL * NS;
  float* sumdl = C_r + (size_t)BB * LL * NS;             // NC2*G2
  unsigned short* xwbf_f = (unsigned short*)(sumdl + (size_t)NC2 * 2 * BB * DN);
  unsigned short* xwbf_r = xwbf_f + 48 * 512;
  float* xz = (float*)(xwbf_r + 48 * 512);  // SZ (x rows; dead after conv)
  float* hend = xz;  // ALIAS: NC2*G2*NS floats = xz region + tail extension
                     // (xz dead after conv_kernel; hend dead before next in_proj)

  for (int s = 0; s < 2; s++) {
    const int p = 4 + s * 14;
    const float* hin = (const float*)d_in[s];
    const float* in_w = (const float*)d_in[p + 0];
    const float* conv_w = (const float*)d_in[p + 1];
    const float* conv_b = (const float*)d_in[p + 2];
    const float* x_w = (const float*)d_in[p + 3];
    const float* dt_w = (const float*)d_in[p + 4];
    const float* dt_b = (const float*)d_in[p + 5];
    const float* Dp = (const float*)d_in[p + 6];
    const float* conv_w_b = (const float*)d_in[p + 7];
    const float* conv_b_b = (const float*)d_in[p + 8];
    const float* x_w_b = (const float*)d_in[p + 9];
    const float* dt_w_b = (const float*)d_in[p + 10];
    const float* dt_b_b = (const float*)d_in[p + 11];
    const float* Dp_b = (const float*)d_in[p + 12];
    const float* out_w = (const float*)d_in[p + 13];
    float* outp = (float*)d_out + (size_t)s * BB * LL * DM;

    hipLaunchKernelGGL(in_proj_mfma, dim3(LL / 128, EE / 128, BB), dim3(256), 0,
                       stream, hin, in_w, xz, z_t);
    hipLaunchKernelGGL(xw_prep_kernel, dim3(96), dim3(256), 0, stream,
                       x_w, x_w_b, xwbf_f, xwbf_r);
    hipLaunchKernelGGL(conv_kernel, dim3((LL / 32) * 4, BB, 2), dim3(256), 0,
                       stream, xz, conv_w, conv_b, conv_w_b, conv_b_b, u_f, u_r);
    hipLaunchKernelGGL(xdbl_kernel, dim3(LL / 16, BB, 2), dim3(256), 0, stream,
                       u_f, u_r, xwbf_f, xwbf_r, dt_w, dt_b, dt_w_b, dt_b_b,
                       dl_f, B_f, C_f, dl_r, B_r, C_r);
    hipLaunchKernelGGL(HIP_KERNEL_NAME(scan_kernel<1>), dim3(NC2 * 16), dim3(256), 0,
                       stream, u_f, u_r, dl_f, dl_r, z_t, B_f, C_f, B_r, C_r, A_log,
                       Ab_log, Dp, Dp_b, hend, sumdl);
    hipLaunchKernelGGL(scan_combine_kernel, dim3(2 * BB * DN / 16), dim3(256),
                       0, stream, A_log, Ab_log, hend, sumdl);
    hipLaunchKernelGGL(HIP_KERNEL_NAME(scan_kernel<3>), dim3(NC2 * 16), dim3(256), 0,
                       stream, u_f, u_r, dl_f, dl_r, z_t, B_f, C_f, B_r, C_r, A_log,
                       Ab_log, Dp, Dp_b, hend, sumdl);
    hipLaunchKernelGGL(out_proj_mfma, dim3(LL / 64, DM / 64, BB), dim3(256), 0,
                       stream, u_f, u_r, out_w, outp);
  }
}

// Round 13
// 404.493 us; speedup vs baseline: 1.1373x; 1.0228x over previous
//
#include <hip/hip_runtime.h>
#include <hip/hip_bf16.h>
#include <cstddef>

#define BB 4
#define LL 2048
#define DM 256
#define DN 512
#define EE 1024
#define NS 16
#define RK 16
#define NC2 128         // scan chunks (8 blocks/CU)
#define CL2 (LL / NC2)  // chunk length = 16

typedef __attribute__((ext_vector_type(8))) short bf16x8;
typedef __attribute__((ext_vector_type(8))) unsigned short ushort8;
typedef __attribute__((ext_vector_type(4))) unsigned short ushort4v;
typedef __attribute__((ext_vector_type(2))) unsigned short ushort2v;
typedef __attribute__((ext_vector_type(4))) float f32x4;

__device__ __forceinline__ float fsilu(float x) { return x / (1.0f + __expf(-x)); }
__device__ __forceinline__ float fsoftplus(float x) { return x > 20.0f ? x : log1pf(__expf(x)); }
__device__ __forceinline__ unsigned short f2bf(float x) {  // RNE float->bf16
  union { float f; unsigned int u; } v; v.f = x;
  unsigned int r = v.u + 0x7fffu + ((v.u >> 16) & 1u);
  return (unsigned short)(r >> 16);
}
__device__ __forceinline__ float bf2f(unsigned short x) {
  union { unsigned int u; float f; } v; v.u = ((unsigned int)x) << 16;
  return v.f;
}

// ---------------------------------------------------------------------------
// in_proj via bf16 MFMA. x-blocks (e<DN): C[e][l] -> xz[b][e][l] fp32.
// z-blocks: swap A/B so C[l][d] -> z_t[b][l][d] = silu, stored BF16.
// ---------------------------------------------------------------------------
__global__ __launch_bounds__(256) void in_proj_mfma(
    const float* __restrict__ h, const float* __restrict__ w,
    float* __restrict__ xz, unsigned short* __restrict__ z_t) {
  __shared__ unsigned short ht[128][40];  // [l][k] bf16
  __shared__ unsigned short wt[128][40];  // [e][k]
  const int b = blockIdx.z;
  const int e0 = blockIdx.y * 128;
  const int l0 = blockIdx.x * 128;
  const int tid = threadIdx.x;
  const int lane = tid & 63;
  const int wid = tid >> 6;
  const int wm = wid >> 1, wn = wid & 1;
  const bool zblk = (e0 >= DN);
  const int krow = (lane >> 4) * 8;
  const int rlo = lane & 15;

  f32x4 acc[4][4];
#pragma unroll
  for (int i = 0; i < 4; i++)
#pragma unroll
    for (int j = 0; j < 4; j++) acc[i][j] = (f32x4){0.f, 0.f, 0.f, 0.f};

  for (int dk = 0; dk < DM; dk += 32) {
#pragma unroll
    for (int it = 0; it < 2; it++) {
      int idx = it * 256 + tid;
      int row = idx >> 2;
      int seg = (idx & 3) * 8;
      const float* hp = h + ((size_t)b * LL + l0 + row) * DM + dk + seg;
      float4 ha = *(const float4*)hp, hb = *(const float4*)(hp + 4);
      ushort8 hv;
      hv[0] = f2bf(ha.x); hv[1] = f2bf(ha.y); hv[2] = f2bf(ha.z); hv[3] = f2bf(ha.w);
      hv[4] = f2bf(hb.x); hv[5] = f2bf(hb.y); hv[6] = f2bf(hb.z); hv[7] = f2bf(hb.w);
      *(ushort8*)&ht[row][seg] = hv;
      const float* wp = w + (size_t)(e0 + row) * DM + dk + seg;
      float4 wa = *(const float4*)wp, wb = *(const float4*)(wp + 4);
      ushort8 wv;
      wv[0] = f2bf(wa.x); wv[1] = f2bf(wa.y); wv[2] = f2bf(wa.z); wv[3] = f2bf(wa.w);
      wv[4] = f2bf(wb.x); wv[5] = f2bf(wb.y); wv[6] = f2bf(wb.z); wv[7] = f2bf(wb.w);
      *(ushort8*)&wt[row][seg] = wv;
    }
    __syncthreads();
    unsigned short (*Ab)[40] = zblk ? ht : wt;
    unsigned short (*Bb)[40] = zblk ? wt : ht;
    bf16x8 af[4], bfr[4];
#pragma unroll
    for (int mt = 0; mt < 4; mt++)
      af[mt] = *(bf16x8*)&Ab[wm * 64 + mt * 16 + rlo][krow];
#pragma unroll
    for (int nt = 0; nt < 4; nt++)
      bfr[nt] = *(bf16x8*)&Bb[wn * 64 + nt * 16 + rlo][krow];
#pragma unroll
    for (int mt = 0; mt < 4; mt++)
#pragma unroll
      for (int nt = 0; nt < 4; nt++)
        acc[mt][nt] = __builtin_amdgcn_mfma_f32_16x16x32_bf16(
            af[mt], bfr[nt], acc[mt][nt], 0, 0, 0);
    __syncthreads();
  }
  if (!zblk) {
#pragma unroll
    for (int mt = 0; mt < 4; mt++)
#pragma unroll
      for (int nt = 0; nt < 4; nt++)
#pragma unroll
        for (int r = 0; r < 4; r++) {
          int e = e0 + wm * 64 + mt * 16 + (lane >> 4) * 4 + r;
          int l = l0 + wn * 64 + nt * 16 + rlo;
          xz[((size_t)b * DN + e) * LL + l] = acc[mt][nt][r];
        }
  } else {
#pragma unroll
    for (int mt = 0; mt < 4; mt++)
#pragma unroll
      for (int nt = 0; nt < 4; nt++)
#pragma unroll
        for (int r = 0; r < 4; r++) {
          int l = l0 + wm * 64 + mt * 16 + (lane >> 4) * 4 + r;
          int d = (e0 - DN) + wn * 64 + nt * 16 + rlo;
          z_t[((size_t)b * LL + l) * DN + d] = f2bf(fsilu(acc[mt][nt][r]));
        }
  }
}

// ---------------------------------------------------------------------------
// conv_kernel: streaming conv+silu+transpose. Writes u[b][l][d] as BF16.
// ---------------------------------------------------------------------------
__global__ __launch_bounds__(256) void conv_kernel(
    const float* __restrict__ xz,
    const float* __restrict__ cw_f, const float* __restrict__ cb_f,
    const float* __restrict__ cw_r, const float* __restrict__ cb_r,
    unsigned short* __restrict__ u_f, unsigned short* __restrict__ u_r) {
  __shared__ float xt[128][33];
  const int rev = blockIdx.z;
  const int b = blockIdx.y;
  const int dc0 = (blockIdx.x & 3) * 128;
  const int l0 = (blockIdx.x >> 2) * 32;
  const int tid = threadIdx.x;
  const int lc = tid & 31;
  const int dg = tid >> 5;  // 0..7
  const int l = l0 + lc;
  const float* conv_w = rev ? cw_r : cw_f;
  const float* conv_b = rev ? cb_r : cb_f;
  unsigned short* u_out = rev ? u_r : u_f;

#pragma unroll
  for (int i = 0; i < 16; i++) {
    int dloc = dg * 16 + i;
    int dd = dc0 + dloc;
    const float* base = xz + ((size_t)b * DN + dd) * LL;
    float4 cw4 = *(const float4*)(conv_w + dd * 4);
    float a0 = conv_b[dd];
    if (rev) {
      a0 = fmaf(cw4.w, base[l], a0);
      if (l + 1 < LL) a0 = fmaf(cw4.z, base[l + 1], a0);
      if (l + 2 < LL) a0 = fmaf(cw4.y, base[l + 2], a0);
      if (l + 3 < LL) a0 = fmaf(cw4.x, base[l + 3], a0);
    } else {
      a0 = fmaf(cw4.w, base[l], a0);
      if (l - 1 >= 0) a0 = fmaf(cw4.z, base[l - 1], a0);
      if (l - 2 >= 0) a0 = fmaf(cw4.y, base[l - 2], a0);
      if (l - 3 >= 0) a0 = fmaf(cw4.x, base[l - 3], a0);
    }
    xt[dloc][lc] = fsilu(a0);
  }
  __syncthreads();
#pragma unroll
  for (int j = 0; j < 8; j++) {
    int idx = j * 256 + tid;  // 0..2047 ushort2 units
    int d2 = idx & 63;        // ushort2 column (d = 2*d2)
    int l2 = idx >> 6;        // 0..31
    ushort2v v;
    v[0] = f2bf(xt[2 * d2][l2]);
    v[1] = f2bf(xt[2 * d2 + 1][l2]);
    *(ushort2v*)&u_out[((size_t)b * LL + l0 + l2) * DN + dc0 + 2 * d2] = v;
  }
}

// ---------------------------------------------------------------------------
// prep: convert x_w (48x512 fp32) of both branches to bf16 global.
// ---------------------------------------------------------------------------
__global__ __launch_bounds__(256) void xw_prep_kernel(
    const float* __restrict__ xw_f, const float* __restrict__ xw_r,
    unsigned short* __restrict__ o_f, unsigned short* __restrict__ o_r) {
  int i = blockIdx.x * 256 + threadIdx.x;
  if (i < 48 * 512) {
    o_f[i] = f2bf(xw_f[i]);
    o_r[i] = f2bf(xw_r[i]);
  }
}

// ---------------------------------------------------------------------------
// xdbl_kernel: x_dbl GEMM (48 x 16l x 512) + fused delta. u now BF16 ->
// staging is a straight ushort8 copy (no convert pass).
// ---------------------------------------------------------------------------
__global__ __launch_bounds__(256) void xdbl_kernel(
    const unsigned short* __restrict__ u_f, const unsigned short* __restrict__ u_r,
    const unsigned short* __restrict__ xwb_f,
    const unsigned short* __restrict__ xwb_r,
    const float* __restrict__ dtw_f, const float* __restrict__ dtb_f,
    const float* __restrict__ dtw_r, const float* __restrict__ dtb_r,
    float* __restrict__ dl_f, float* __restrict__ B_f, float* __restrict__ C_f,
    float* __restrict__ dl_r, float* __restrict__ B_r, float* __restrict__ C_r) {
  __shared__ __align__(16) unsigned short ub[4][16][136];  // u tile, per k-chunk
  __shared__ float red[4][48][17];                         // per-wave partials
  __shared__ float dtv[16][17];                            // dt rows
  const int rev = blockIdx.z;
  const int b = blockIdx.y;
  const int l0 = blockIdx.x * 16;
  const int tid = threadIdx.x;
  const int lane = tid & 63;
  const int w = tid >> 6;  // wave = k-chunk 0..3
  const int rlo = lane & 15;
  const int hi4 = lane >> 4;  // 0..3
  const int kseg = hi4 * 8;

  const unsigned short* up = (rev ? u_r : u_f) + ((size_t)b * LL + l0) * DN;
  const unsigned short* xwb = rev ? xwb_r : xwb_f;
  const float* dt_w = rev ? dtw_r : dtw_f;
  const float* dt_b = rev ? dtb_r : dtb_f;
  float* dl_out = rev ? dl_r : dl_f;
  float* B_out = rev ? B_r : B_f;
  float* C_out = rev ? C_r : C_f;

  // stage u tile [16 l][512 d] (already bf16): pure copy
#pragma unroll
  for (int j = 0; j < 4; j++) {
    int idx = j * 256 + tid;  // 0..1023 ushort8 units
    int l2 = idx >> 6;        // 0..15
    int c8 = idx & 63;        // ushort8 col
    ushort8 v = *(const ushort8*)(up + (size_t)l2 * DN + c8 * 8);
    *(ushort8*)&ub[c8 >> 4][l2][(c8 & 15) * 8] = v;
  }
  __syncthreads();

  f32x4 am0 = (f32x4){0.f, 0.f, 0.f, 0.f};
  f32x4 am1 = (f32x4){0.f, 0.f, 0.f, 0.f};
  f32x4 am2 = (f32x4){0.f, 0.f, 0.f, 0.f};
#pragma unroll
  for (int ks = 0; ks < 4; ks++) {
    bf16x8 bfrag = *(bf16x8*)&ub[w][rlo][ks * 32 + kseg];
    const unsigned short* xp = xwb + (size_t)(w * 128 + ks * 32 + kseg);
    bf16x8 a0 = *(const bf16x8*)(xp + (size_t)(0 + rlo) * 512);
    bf16x8 a1 = *(const bf16x8*)(xp + (size_t)(16 + rlo) * 512);
    bf16x8 a2 = *(const bf16x8*)(xp + (size_t)(32 + rlo) * 512);
    am0 = __builtin_amdgcn_mfma_f32_16x16x32_bf16(a0, bfrag, am0, 0, 0, 0);
    am1 = __builtin_amdgcn_mfma_f32_16x16x32_bf16(a1, bfrag, am1, 0, 0, 0);
    am2 = __builtin_amdgcn_mfma_f32_16x16x32_bf16(a2, bfrag, am2, 0, 0, 0);
  }
  {
    const int rbase = hi4 * 4;
#pragma unroll
    for (int r = 0; r < 4; r++) red[w][0 + rbase + r][rlo] = am0[r];
#pragma unroll
    for (int r = 0; r < 4; r++) red[w][16 + rbase + r][rlo] = am1[r];
#pragma unroll
    for (int r = 0; r < 4; r++) red[w][32 + rbase + r][rlo] = am2[r];
  }
  __syncthreads();
#pragma unroll
  for (int i = 0; i < 3; i++) {
    int o = i * 256 + tid;  // 0..767
    int row = o >> 4, col = o & 15;
    float s = (red[0][row][col] + red[1][row][col]) +
              (red[2][row][col] + red[3][row][col]);
    if (row < 16)
      dtv[row][col] = s;
    else if (row < 32)
      B_out[((size_t)b * LL + l0 + col) * NS + (row - 16)] = s;
    else
      C_out[((size_t)b * LL + l0 + col) * NS + (row - 32)] = s;
  }
  __syncthreads();
  // delta: thread handles d = tid and tid+256, all 16 l (fp32 exact path)
#pragma unroll
  for (int half = 0; half < 2; half++) {
    int dd = half * 256 + tid;
    const float4* wr = (const float4*)(dt_w + (size_t)dd * RK);
    float4 w0 = wr[0], w1 = wr[1], w2 = wr[2], w3 = wr[3];
    float bias = dt_b[dd];
#pragma unroll
    for (int l2 = 0; l2 < 16; l2++) {
      float a0 = bias;
      a0 = fmaf(w0.x, dtv[0][l2], a0);  a0 = fmaf(w0.y, dtv[1][l2], a0);
      a0 = fmaf(w0.z, dtv[2][l2], a0);  a0 = fmaf(w0.w, dtv[3][l2], a0);
      a0 = fmaf(w1.x, dtv[4][l2], a0);  a0 = fmaf(w1.y, dtv[5][l2], a0);
      a0 = fmaf(w1.z, dtv[6][l2], a0);  a0 = fmaf(w1.w, dtv[7][l2], a0);
      a0 = fmaf(w2.x, dtv[8][l2], a0);  a0 = fmaf(w2.y, dtv[9][l2], a0);
      a0 = fmaf(w2.z, dtv[10][l2], a0); a0 = fmaf(w2.w, dtv[11][l2], a0);
      a0 = fmaf(w3.x, dtv[12][l2], a0); a0 = fmaf(w3.y, dtv[13][l2], a0);
      a0 = fmaf(w3.z, dtv[14][l2], a0); a0 = fmaf(w3.w, dtv[15][l2], a0);
      dl_out[((size_t)b * LL + l0 + l2) * DN + dd] = fsoftplus(a0);
    }
  }
}

// ---------------------------------------------------------------------------
// Scan: lane = channel d, 16 states in registers. u/z/y BF16, dl fp32.
// B/C [b][t][n] wave-uniform float4, all streams prefetched 1 step ahead.
// y written in place over u. NC2=128 -> 8 blk/CU.
// ---------------------------------------------------------------------------
#define HSTEP(n, Bcomp, Ccomp)                      \
  {                                                 \
    float e_ = __expf(dc * Av[n]);                  \
    h[n] = fmaf(e_, h[n], dlu * (Bcomp));           \
    if (PHASE == 3) acc = fmaf(h[n], (Ccomp), acc); \
  }

template <int PHASE>
__global__ __launch_bounds__(256) void scan_kernel(
    unsigned short* __restrict__ uy_f, unsigned short* __restrict__ uy_r,
    const float* __restrict__ dl_f, const float* __restrict__ dl_r,
    const unsigned short* __restrict__ z_t, const float* __restrict__ B_f,
    const float* __restrict__ C_f, const float* __restrict__ B_r,
    const float* __restrict__ C_r, const float* __restrict__ A_log,
    const float* __restrict__ Ab_log, const float* __restrict__ D_f,
    const float* __restrict__ D_r, float* __restrict__ hend,
    float* __restrict__ sumdl) {
  const int G2 = 2 * BB * DN;                            // 4096
  const int ch = (blockIdx.x & 15) * 256 + threadIdx.x;  // channel
  const int chunk = blockIdx.x >> 4;                     // 0..NC2-1
  const bool rev = ch >= BB * DN;                        // uniform per block
  const int cid = rev ? ch - BB * DN : ch;
  const int b = cid >> 9;
  const int d = cid & (DN - 1);

  const float* Arow = (rev ? Ab_log : A_log) + d * NS;
  float Av[NS];
#pragma unroll
  for (int n = 0; n < NS; n++) Av[n] = -__expf(Arow[n]);
  const float Dd = (rev ? D_r : D_f)[d];

  unsigned short* uy = (rev ? uy_r : uy_f) + (size_t)b * LL * DN + d;
  const float* dlp = (rev ? dl_r : dl_f) + (size_t)b * LL * DN + d;
  const float* Bp = (rev ? B_r : B_f) + (size_t)b * LL * NS;
  const float* Cp = (rev ? C_r : C_f) + (size_t)b * LL * NS;
  const unsigned short* zp = z_t + (size_t)b * LL * DN + d;

  float h[NS];
  if (PHASE == 3) {
    const float* hp = hend + ((size_t)chunk * G2 + ch) * NS;
#pragma unroll
    for (int n = 0; n < NS; n++) h[n] = hp[n];
  } else {
#pragma unroll
    for (int n = 0; n < NS; n++) h[n] = 0.f;
  }

  const int tstep = rev ? -1 : 1;
  int t = rev ? (LL - 1 - CL2 * chunk) : (CL2 * chunk);
  float sdl = 0.f;
  float uc = bf2f(uy[(size_t)t * DN]);
  float dc = dlp[(size_t)t * DN];
  float zc = (PHASE == 3) ? bf2f(zp[(size_t)t * DN]) : 0.f;
  const float4* Bt4 = (const float4*)(Bp + (size_t)t * NS);
  float4 cB0 = Bt4[0], cB1 = Bt4[1], cB2 = Bt4[2], cB3 = Bt4[3];
  float4 cC0 = {0, 0, 0, 0}, cC1 = {0, 0, 0, 0}, cC2 = {0, 0, 0, 0},
         cC3 = {0, 0, 0, 0};
  if (PHASE == 3) {
    const float4* Ct4 = (const float4*)(Cp + (size_t)t * NS);
    cC0 = Ct4[0]; cC1 = Ct4[1]; cC2 = Ct4[2]; cC3 = Ct4[3];
  }

  for (int s = 0; s < CL2; s++) {
    int tn = t + tstep;
    int tcl = tn < 0 ? 0 : (tn >= LL ? LL - 1 : tn);
    float un = bf2f(uy[(size_t)tcl * DN]);
    float dn_ = dlp[(size_t)tcl * DN];
    float zn = (PHASE == 3) ? bf2f(zp[(size_t)tcl * DN]) : 0.f;
    const float4* Bn4 = (const float4*)(Bp + (size_t)tcl * NS);
    float4 nB0 = Bn4[0], nB1 = Bn4[1], nB2 = Bn4[2], nB3 = Bn4[3];
    float4 nC0 = {0, 0, 0, 0}, nC1 = {0, 0, 0, 0}, nC2 = {0, 0, 0, 0},
           nC3 = {0, 0, 0, 0};
    if (PHASE == 3) {
      const float4* Cn4 = (const float4*)(Cp + (size_t)tcl * NS);
      nC0 = Cn4[0]; nC1 = Cn4[1]; nC2 = Cn4[2]; nC3 = Cn4[3];
    }
    const float dlu = dc * uc;
    float acc = 0.f;
    HSTEP(0, cB0.x, cC0.x)  HSTEP(1, cB0.y, cC0.y)
    HSTEP(2, cB0.z, cC0.z)  HSTEP(3, cB0.w, cC0.w)
    HSTEP(4, cB1.x, cC1.x)  HSTEP(5, cB1.y, cC1.y)
    HSTEP(6, cB1.z, cC1.z)  HSTEP(7, cB1.w, cC1.w)
    HSTEP(8, cB2.x, cC2.x)  HSTEP(9, cB2.y, cC2.y)
    HSTEP(10, cB2.z, cC2.z) HSTEP(11, cB2.w, cC2.w)
    HSTEP(12, cB3.x, cC3.x) HSTEP(13, cB3.y, cC3.y)
    HSTEP(14, cB3.z, cC3.z) HSTEP(15, cB3.w, cC3.w)
    if (PHASE == 1) sdl += dc;
    if (PHASE == 3) {
      float y = fmaf(uc, Dd, acc) * zc;
      uy[(size_t)t * DN] = f2bf(y);
    }
    t = tn; uc = un; dc = dn_; zc = zn;
    cB0 = nB0; cB1 = nB1; cB2 = nB2; cB3 = nB3;
    if (PHASE == 3) { cC0 = nC0; cC1 = nC1; cC2 = nC2; cC3 = nC3; }
  }
  if (PHASE == 1) {
    float* hp = hend + ((size_t)chunk * G2 + ch) * NS;
#pragma unroll
    for (int n = 0; n < NS; n++) hp[n] = h[n];
    sumdl[(size_t)chunk * G2 + ch] = sdl;
  }
}
#undef HSTEP

// ---------------------------------------------------------------------------
// Phase 2 (in-place, LDS-tiled): batch-loaded slabs keep global loads off the
// dependent chain.
// ---------------------------------------------------------------------------
__global__ __launch_bounds__(256) void scan_combine_kernel(
    const float* __restrict__ A_log, const float* __restrict__ Ab_log,
    float* __restrict__ hend, const float* __restrict__ sumdl) {
  const int G2 = 2 * BB * DN;
  __shared__ float tile[8][256];
  __shared__ float sd[8][16];
  const int tid = threadIdx.x;
  const int ch0 = blockIdx.x * 16;
  const int chl = tid >> 4;  // local channel 0..15
  const int n = tid & 15;
  const int ch = ch0 + chl;
  const bool rev = ch >= BB * DN;
  const int d = ch & (DN - 1);
  const float Av = -__expf((rev ? Ab_log : A_log)[d * NS + n]);
  float H = 0.f;
  for (int cb = 0; cb < NC2 / 8; cb++) {
#pragma unroll
    for (int j = 0; j < 8; j++)
      tile[j][tid] = hend[((size_t)(cb * 8 + j) * G2 + ch0) * NS + tid];
    if (tid < 128) {
      int j = tid >> 4, k = tid & 15;
      sd[j][k] = sumdl[(size_t)(cb * 8 + j) * G2 + ch0 + k];
    }
    __syncthreads();
#pragma unroll
    for (int j = 0; j < 8; j++) {
      float tmp = tile[j][tid];
      tile[j][tid] = H;
      H = fmaf(__expf(Av * sd[j][chl]), H, tmp);
    }
    __syncthreads();
#pragma unroll
    for (int j = 0; j < 8; j++)
      hend[((size_t)(cb * 8 + j) * G2 + ch0) * NS + tid] = tile[j][tid];
    __syncthreads();
  }
}

// ---------------------------------------------------------------------------
// out_proj via bf16 MFMA: y now BF16 [b][l][d] -> direct ushort8 loads.
// ---------------------------------------------------------------------------
__global__ __launch_bounds__(256) void out_proj_mfma(
    const unsigned short* __restrict__ yf, const unsigned short* __restrict__ yr,
    const float* __restrict__ ow, float* __restrict__ outp) {
  __shared__ unsigned short yt[64][40];
  __shared__ unsigned short wo[64][40];
  const int b = blockIdx.z;
  const int m0 = blockIdx.y * 64;
  const int l0 = blockIdx.x * 64;
  const int tid = threadIdx.x;
  const int lane = tid & 63;
  const int wid = tid >> 6;
  const int wm = wid >> 1, wn = wid & 1;
  const int krow = (lane >> 4) * 8;
  const int rlo = lane & 15;

  f32x4 acc[2][2];
#pragma unroll
  for (int i = 0; i < 2; i++)
#pragma unroll
    for (int j = 0; j < 2; j++) acc[i][j] = (f32x4){0.f, 0.f, 0.f, 0.f};

  for (int dk = 0; dk < DN; dk += 32) {
    {
      int row = tid >> 2;
      int seg = (tid & 3) * 8;
      ushort8 a = *(const ushort8*)(yf + ((size_t)b * LL + l0 + row) * DN + dk + seg);
      ushort8 c = *(const ushort8*)(yr + ((size_t)b * LL + l0 + row) * DN + dk + seg);
      ushort8 yv;
#pragma unroll
      for (int k = 0; k < 8; k++) yv[k] = f2bf(0.5f * (bf2f(a[k]) + bf2f(c[k])));
      *(ushort8*)&yt[row][seg] = yv;
      const float* wp = ow + (size_t)(m0 + row) * DN + dk + seg;
      float4 w0 = *(const float4*)wp, w1 = *(const float4*)(wp + 4);
      ushort8 wv;
      wv[0] = f2bf(w0.x); wv[1] = f2bf(w0.y); wv[2] = f2bf(w0.z); wv[3] = f2bf(w0.w);
      wv[4] = f2bf(w1.x); wv[5] = f2bf(w1.y); wv[6] = f2bf(w1.z); wv[7] = f2bf(w1.w);
      *(ushort8*)&wo[row][seg] = wv;
    }
    __syncthreads();
    bf16x8 a0 = *(bf16x8*)&yt[wm * 32 + rlo][krow];
    bf16x8 a1 = *(bf16x8*)&yt[wm * 32 + 16 + rlo][krow];
    bf16x8 b0 = *(bf16x8*)&wo[wn * 32 + rlo][krow];
    bf16x8 b1 = *(bf16x8*)&wo[wn * 32 + 16 + rlo][krow];
    acc[0][0] = __builtin_amdgcn_mfma_f32_16x16x32_bf16(a0, b0, acc[0][0], 0, 0, 0);
    acc[0][1] = __builtin_amdgcn_mfma_f32_16x16x32_bf16(a0, b1, acc[0][1], 0, 0, 0);
    acc[1][0] = __builtin_amdgcn_mfma_f32_16x16x32_bf16(a1, b0, acc[1][0], 0, 0, 0);
    acc[1][1] = __builtin_amdgcn_mfma_f32_16x16x32_bf16(a1, b1, acc[1][1], 0, 0, 0);
    __syncthreads();
  }
#pragma unroll
  for (int mt = 0; mt < 2; mt++)
#pragma unroll
    for (int nt = 0; nt < 2; nt++)
#pragma unroll
      for (int r = 0; r < 4; r++) {
        int l = l0 + wm * 32 + mt * 16 + (lane >> 4) * 4 + r;
        int m = m0 + wn * 32 + nt * 16 + rlo;
        outp[((size_t)b * LL + l) * DM + m] = acc[mt][nt][r];
      }
}

// ---------------------------------------------------------------------------
extern "C" void kernel_launch(void* const* d_in, const int* in_sizes, int n_in,
                              void* d_out, int out_size, void* d_ws, size_t ws_size,
                              hipStream_t stream) {
  (void)in_sizes; (void)n_in; (void)out_size; (void)ws_size;
  const float* A_log = (const float*)d_in[2];
  const float* Ab_log = (const float*)d_in[3];

  const size_t SZ = (size_t)BB * LL * DN;      // 4,194,304 elements
  const size_t NSZ = (size_t)BB * LL * NS;     // 131,072
  float* ws = (float*)d_ws;
  float* dl_f = ws;                            // SZ fp32
  float* dl_r = dl_f + SZ;                     // SZ fp32
  float* B_f = dl_r + SZ;                      // NSZ
  float* C_f = B_f + NSZ;
  float* B_r = C_f + NSZ;
  float* C_r = B_r + NSZ;
  float* sumdl = C_r + NSZ;                    // NC2*G2 = 524,288
  unsigned short* xwbf_f = (unsigned short*)(sumdl + (size_t)NC2 * 2 * BB * DN);
  unsigned short* xwbf_r = xwbf_f + 48 * 512;
  unsigned short* z_t = xwbf_r + 48 * 512;     // SZ bf16
  unsigned short* u_f = z_t + SZ;              // SZ bf16 (u -> y in place)
  unsigned short* u_r = u_f + SZ;              // SZ bf16
  float* xz = (float*)(u_r + SZ);              // SZ fp32 (dead after conv)
  float* hend = xz;  // ALIAS: NC2*G2*NS floats (xz region + tail extension)

  for (int s = 0; s < 2; s++) {
    const int p = 4 + s * 14;
    const float* hin = (const float*)d_in[s];
    const float* in_w = (const float*)d_in[p + 0];
    const float* conv_w = (const float*)d_in[p + 1];
    const float* conv_b = (const float*)d_in[p + 2];
    const float* x_w = (const float*)d_in[p + 3];
    const float* dt_w = (const float*)d_in[p + 4];
    const float* dt_b = (const float*)d_in[p + 5];
    const float* Dp = (const float*)d_in[p + 6];
    const float* conv_w_b = (const float*)d_in[p + 7];
    const float* conv_b_b = (const float*)d_in[p + 8];
    const float* x_w_b = (const float*)d_in[p + 9];
    const float* dt_w_b = (const float*)d_in[p + 10];
    const float* dt_b_b = (const float*)d_in[p + 11];
    const float* Dp_b = (const float*)d_in[p + 12];
    const float* out_w = (const float*)d_in[p + 13];
    float* outp = (float*)d_out + (size_t)s * BB * LL * DM;

    hipLaunchKernelGGL(in_proj_mfma, dim3(LL / 128, EE / 128, BB), dim3(256), 0,
                       stream, hin, in_w, xz, z_t);
    hipLaunchKernelGGL(xw_prep_kernel, dim3(96), dim3(256), 0, stream,
                       x_w, x_w_b, xwbf_f, xwbf_r);
    hipLaunchKernelGGL(conv_kernel, dim3((LL / 32) * 4, BB, 2), dim3(256), 0,
                       stream, xz, conv_w, conv_b, conv_w_b, conv_b_b, u_f, u_r);
    hipLaunchKernelGGL(xdbl_kernel, dim3(LL / 16, BB, 2), dim3(256), 0, stream,
                       u_f, u_r, xwbf_f, xwbf_r, dt_w, dt_b, dt_w_b, dt_b_b,
                       dl_f, B_f, C_f, dl_r, B_r, C_r);
    hipLaunchKernelGGL(HIP_KERNEL_NAME(scan_kernel<1>), dim3(NC2 * 16), dim3(256), 0,
                       stream, u_f, u_r, dl_f, dl_r, z_t, B_f, C_f, B_r, C_r, A_log,
                       Ab_log, Dp, Dp_b, hend, sumdl);
    hipLaunchKernelGGL(scan_combine_kernel, dim3(2 * BB * DN / 16), dim3(256),
                       0, stream, A_log, Ab_log, hend, sumdl);
    hipLaunchKernelGGL(HIP_KERNEL_NAME(scan_kernel<3>), dim3(NC2 * 16), dim3(256), 0,
                       stream, u_f, u_r, dl_f, dl_r, z_t, B_f, C_f, B_r, C_r, A_log,
                       Ab_log, Dp, Dp_b, hend, sumdl);
    hipLaunchKernelGGL(out_proj_mfma, dim3(LL / 64, DM / 64, BB), dim3(256), 0,
                       stream, u_f, u_r, out_w, outp);
  }
}

// Round 14
// 404.210 us; speedup vs baseline: 1.1381x; 1.0007x over previous
//
#include <hip/hip_runtime.h>
#include <hip/hip_bf16.h>
#include <cstddef>

#define BB 4
#define LL 2048
#define DM 256
#define DN 512
#define EE 1024
#define NS 16
#define RK 16
#define NC2 128         // scan chunks (8 blocks/CU)
#define CL2 (LL / NC2)  // chunk length = 16

typedef __attribute__((ext_vector_type(8))) short bf16x8;
typedef __attribute__((ext_vector_type(8))) unsigned short ushort8;
typedef __attribute__((ext_vector_type(4))) unsigned short ushort4v;
typedef __attribute__((ext_vector_type(2))) unsigned short ushort2v;
typedef __attribute__((ext_vector_type(4))) float f32x4;

__device__ __forceinline__ float fsilu(float x) { return x / (1.0f + __expf(-x)); }
__device__ __forceinline__ float fsoftplus(float x) { return x > 20.0f ? x : log1pf(__expf(x)); }
__device__ __forceinline__ unsigned short f2bf(float x) {  // RNE float->bf16
  union { float f; unsigned int u; } v; v.f = x;
  unsigned int r = v.u + 0x7fffu + ((v.u >> 16) & 1u);
  return (unsigned short)(r >> 16);
}
__device__ __forceinline__ float bf2f(unsigned short x) {
  union { unsigned int u; float f; } v; v.u = ((unsigned int)x) << 16;
  return v.f;
}

// ---------------------------------------------------------------------------
// in_proj via bf16 MFMA. x-blocks (e<DN): C[e][l] -> xz[b][e][l] fp32.
// z-blocks: swap A/B so C[l][d] -> z_t[b][l][d] = silu, stored BF16.
// ---------------------------------------------------------------------------
__global__ __launch_bounds__(256) void in_proj_mfma(
    const float* __restrict__ h, const float* __restrict__ w,
    float* __restrict__ xz, unsigned short* __restrict__ z_t) {
  __shared__ unsigned short ht[128][40];  // [l][k] bf16
  __shared__ unsigned short wt[128][40];  // [e][k]
  const int b = blockIdx.z;
  const int e0 = blockIdx.y * 128;
  const int l0 = blockIdx.x * 128;
  const int tid = threadIdx.x;
  const int lane = tid & 63;
  const int wid = tid >> 6;
  const int wm = wid >> 1, wn = wid & 1;
  const bool zblk = (e0 >= DN);
  const int krow = (lane >> 4) * 8;
  const int rlo = lane & 15;

  f32x4 acc[4][4];
#pragma unroll
  for (int i = 0; i < 4; i++)
#pragma unroll
    for (int j = 0; j < 4; j++) acc[i][j] = (f32x4){0.f, 0.f, 0.f, 0.f};

  for (int dk = 0; dk < DM; dk += 32) {
#pragma unroll
    for (int it = 0; it < 2; it++) {
      int idx = it * 256 + tid;
      int row = idx >> 2;
      int seg = (idx & 3) * 8;
      const float* hp = h + ((size_t)b * LL + l0 + row) * DM + dk + seg;
      float4 ha = *(const float4*)hp, hb = *(const float4*)(hp + 4);
      ushort8 hv;
      hv[0] = f2bf(ha.x); hv[1] = f2bf(ha.y); hv[2] = f2bf(ha.z); hv[3] = f2bf(ha.w);
      hv[4] = f2bf(hb.x); hv[5] = f2bf(hb.y); hv[6] = f2bf(hb.z); hv[7] = f2bf(hb.w);
      *(ushort8*)&ht[row][seg] = hv;
      const float* wp = w + (size_t)(e0 + row) * DM + dk + seg;
      float4 wa = *(const float4*)wp, wb = *(const float4*)(wp + 4);
      ushort8 wv;
      wv[0] = f2bf(wa.x); wv[1] = f2bf(wa.y); wv[2] = f2bf(wa.z); wv[3] = f2bf(wa.w);
      wv[4] = f2bf(wb.x); wv[5] = f2bf(wb.y); wv[6] = f2bf(wb.z); wv[7] = f2bf(wb.w);
      *(ushort8*)&wt[row][seg] = wv;
    }
    __syncthreads();
    unsigned short (*Ab)[40] = zblk ? ht : wt;
    unsigned short (*Bb)[40] = zblk ? wt : ht;
    bf16x8 af[4], bfr[4];
#pragma unroll
    for (int mt = 0; mt < 4; mt++)
      af[mt] = *(bf16x8*)&Ab[wm * 64 + mt * 16 + rlo][krow];
#pragma unroll
    for (int nt = 0; nt < 4; nt++)
      bfr[nt] = *(bf16x8*)&Bb[wn * 64 + nt * 16 + rlo][krow];
#pragma unroll
    for (int mt = 0; mt < 4; mt++)
#pragma unroll
      for (int nt = 0; nt < 4; nt++)
        acc[mt][nt] = __builtin_amdgcn_mfma_f32_16x16x32_bf16(
            af[mt], bfr[nt], acc[mt][nt], 0, 0, 0);
    __syncthreads();
  }
  if (!zblk) {
#pragma unroll
    for (int mt = 0; mt < 4; mt++)
#pragma unroll
      for (int nt = 0; nt < 4; nt++)
#pragma unroll
        for (int r = 0; r < 4; r++) {
          int e = e0 + wm * 64 + mt * 16 + (lane >> 4) * 4 + r;
          int l = l0 + wn * 64 + nt * 16 + rlo;
          xz[((size_t)b * DN + e) * LL + l] = acc[mt][nt][r];
        }
  } else {
#pragma unroll
    for (int mt = 0; mt < 4; mt++)
#pragma unroll
      for (int nt = 0; nt < 4; nt++)
#pragma unroll
        for (int r = 0; r < 4; r++) {
          int l = l0 + wm * 64 + mt * 16 + (lane >> 4) * 4 + r;
          int d = (e0 - DN) + wn * 64 + nt * 16 + rlo;
          z_t[((size_t)b * LL + l) * DN + d] = f2bf(fsilu(acc[mt][nt][r]));
        }
  }
}

// ---------------------------------------------------------------------------
// conv_kernel: streaming conv+silu+transpose. Writes u[b][l][d] as BF16.
// ---------------------------------------------------------------------------
__global__ __launch_bounds__(256) void conv_kernel(
    const float* __restrict__ xz,
    const float* __restrict__ cw_f, const float* __restrict__ cb_f,
    const float* __restrict__ cw_r, const float* __restrict__ cb_r,
    unsigned short* __restrict__ u_f, unsigned short* __restrict__ u_r) {
  __shared__ float xt[128][33];
  const int rev = blockIdx.z;
  const int b = blockIdx.y;
  const int dc0 = (blockIdx.x & 3) * 128;
  const int l0 = (blockIdx.x >> 2) * 32;
  const int tid = threadIdx.x;
  const int lc = tid & 31;
  const int dg = tid >> 5;  // 0..7
  const int l = l0 + lc;
  const float* conv_w = rev ? cw_r : cw_f;
  const float* conv_b = rev ? cb_r : cb_f;
  unsigned short* u_out = rev ? u_r : u_f;

#pragma unroll
  for (int i = 0; i < 16; i++) {
    int dloc = dg * 16 + i;
    int dd = dc0 + dloc;
    const float* base = xz + ((size_t)b * DN + dd) * LL;
    float4 cw4 = *(const float4*)(conv_w + dd * 4);
    float a0 = conv_b[dd];
    if (rev) {
      a0 = fmaf(cw4.w, base[l], a0);
      if (l + 1 < LL) a0 = fmaf(cw4.z, base[l + 1], a0);
      if (l + 2 < LL) a0 = fmaf(cw4.y, base[l + 2], a0);
      if (l + 3 < LL) a0 = fmaf(cw4.x, base[l + 3], a0);
    } else {
      a0 = fmaf(cw4.w, base[l], a0);
      if (l - 1 >= 0) a0 = fmaf(cw4.z, base[l - 1], a0);
      if (l - 2 >= 0) a0 = fmaf(cw4.y, base[l - 2], a0);
      if (l - 3 >= 0) a0 = fmaf(cw4.x, base[l - 3], a0);
    }
    xt[dloc][lc] = fsilu(a0);
  }
  __syncthreads();
#pragma unroll
  for (int j = 0; j < 8; j++) {
    int idx = j * 256 + tid;  // 0..2047 ushort2 units
    int d2 = idx & 63;        // ushort2 column (d = 2*d2)
    int l2 = idx >> 6;        // 0..31
    ushort2v v;
    v[0] = f2bf(xt[2 * d2][l2]);
    v[1] = f2bf(xt[2 * d2 + 1][l2]);
    *(ushort2v*)&u_out[((size_t)b * LL + l0 + l2) * DN + dc0 + 2 * d2] = v;
  }
}

// ---------------------------------------------------------------------------
// prep: convert x_w (48x512 fp32) of both branches to bf16 global.
// ---------------------------------------------------------------------------
__global__ __launch_bounds__(256) void xw_prep_kernel(
    const float* __restrict__ xw_f, const float* __restrict__ xw_r,
    unsigned short* __restrict__ o_f, unsigned short* __restrict__ o_r) {
  int i = blockIdx.x * 256 + threadIdx.x;
  if (i < 48 * 512) {
    o_f[i] = f2bf(xw_f[i]);
    o_r[i] = f2bf(xw_r[i]);
  }
}

// ---------------------------------------------------------------------------
// xdbl_kernel: x_dbl GEMM (48 x 16l x 512) + fused delta. u now BF16 ->
// staging is a straight ushort8 copy (no convert pass).
// ---------------------------------------------------------------------------
__global__ __launch_bounds__(256) void xdbl_kernel(
    const unsigned short* __restrict__ u_f, const unsigned short* __restrict__ u_r,
    const unsigned short* __restrict__ xwb_f,
    const unsigned short* __restrict__ xwb_r,
    const float* __restrict__ dtw_f, const float* __restrict__ dtb_f,
    const float* __restrict__ dtw_r, const float* __restrict__ dtb_r,
    float* __restrict__ dl_f, float* __restrict__ B_f, float* __restrict__ C_f,
    float* __restrict__ dl_r, float* __restrict__ B_r, float* __restrict__ C_r) {
  __shared__ __align__(16) unsigned short ub[4][16][136];  // u tile, per k-chunk
  __shared__ float red[4][48][17];                         // per-wave partials
  __shared__ float dtv[16][17];                            // dt rows
  const int rev = blockIdx.z;
  const int b = blockIdx.y;
  const int l0 = blockIdx.x * 16;
  const int tid = threadIdx.x;
  const int lane = tid & 63;
  const int w = tid >> 6;  // wave = k-chunk 0..3
  const int rlo = lane & 15;
  const int hi4 = lane >> 4;  // 0..3
  const int kseg = hi4 * 8;

  const unsigned short* up = (rev ? u_r : u_f) + ((size_t)b * LL + l0) * DN;
  const unsigned short* xwb = rev ? xwb_r : xwb_f;
  const float* dt_w = rev ? dtw_r : dtw_f;
  const float* dt_b = rev ? dtb_r : dtb_f;
  float* dl_out = rev ? dl_r : dl_f;
  float* B_out = rev ? B_r : B_f;
  float* C_out = rev ? C_r : C_f;

  // stage u tile [16 l][512 d] (already bf16): pure copy
#pragma unroll
  for (int j = 0; j < 4; j++) {
    int idx = j * 256 + tid;  // 0..1023 ushort8 units
    int l2 = idx >> 6;        // 0..15
    int c8 = idx & 63;        // ushort8 col
    ushort8 v = *(const ushort8*)(up + (size_t)l2 * DN + c8 * 8);
    *(ushort8*)&ub[c8 >> 4][l2][(c8 & 15) * 8] = v;
  }
  __syncthreads();

  f32x4 am0 = (f32x4){0.f, 0.f, 0.f, 0.f};
  f32x4 am1 = (f32x4){0.f, 0.f, 0.f, 0.f};
  f32x4 am2 = (f32x4){0.f, 0.f, 0.f, 0.f};
#pragma unroll
  for (int ks = 0; ks < 4; ks++) {
    bf16x8 bfrag = *(bf16x8*)&ub[w][rlo][ks * 32 + kseg];
    const unsigned short* xp = xwb + (size_t)(w * 128 + ks * 32 + kseg);
    bf16x8 a0 = *(const bf16x8*)(xp + (size_t)(0 + rlo) * 512);
    bf16x8 a1 = *(const bf16x8*)(xp + (size_t)(16 + rlo) * 512);
    bf16x8 a2 = *(const bf16x8*)(xp + (size_t)(32 + rlo) * 512);
    am0 = __builtin_amdgcn_mfma_f32_16x16x32_bf16(a0, bfrag, am0, 0, 0, 0);
    am1 = __builtin_amdgcn_mfma_f32_16x16x32_bf16(a1, bfrag, am1, 0, 0, 0);
    am2 = __builtin_amdgcn_mfma_f32_16x16x32_bf16(a2, bfrag, am2, 0, 0, 0);
  }
  {
    const int rbase = hi4 * 4;
#pragma unroll
    for (int r = 0; r < 4; r++) red[w][0 + rbase + r][rlo] = am0[r];
#pragma unroll
    for (int r = 0; r < 4; r++) red[w][16 + rbase + r][rlo] = am1[r];
#pragma unroll
    for (int r = 0; r < 4; r++) red[w][32 + rbase + r][rlo] = am2[r];
  }
  __syncthreads();
#pragma unroll
  for (int i = 0; i < 3; i++) {
    int o = i * 256 + tid;  // 0..767
    int row = o >> 4, col = o & 15;
    float s = (red[0][row][col] + red[1][row][col]) +
              (red[2][row][col] + red[3][row][col]);
    if (row < 16)
      dtv[row][col] = s;
    else if (row < 32)
      B_out[((size_t)b * LL + l0 + col) * NS + (row - 16)] = s;
    else
      C_out[((size_t)b * LL + l0 + col) * NS + (row - 32)] = s;
  }
  __syncthreads();
  // delta: thread handles d = tid and tid+256, all 16 l (fp32 exact path)
#pragma unroll
  for (int half = 0; half < 2; half++) {
    int dd = half * 256 + tid;
    const float4* wr = (const float4*)(dt_w + (size_t)dd * RK);
    float4 w0 = wr[0], w1 = wr[1], w2 = wr[2], w3 = wr[3];
    float bias = dt_b[dd];
#pragma unroll
    for (int l2 = 0; l2 < 16; l2++) {
      float a0 = bias;
      a0 = fmaf(w0.x, dtv[0][l2], a0);  a0 = fmaf(w0.y, dtv[1][l2], a0);
      a0 = fmaf(w0.z, dtv[2][l2], a0);  a0 = fmaf(w0.w, dtv[3][l2], a0);
      a0 = fmaf(w1.x, dtv[4][l2], a0);  a0 = fmaf(w1.y, dtv[5][l2], a0);
      a0 = fmaf(w1.z, dtv[6][l2], a0);  a0 = fmaf(w1.w, dtv[7][l2], a0);
      a0 = fmaf(w2.x, dtv[8][l2], a0);  a0 = fmaf(w2.y, dtv[9][l2], a0);
      a0 = fmaf(w2.z, dtv[10][l2], a0); a0 = fmaf(w2.w, dtv[11][l2], a0);
      a0 = fmaf(w3.x, dtv[12][l2], a0); a0 = fmaf(w3.y, dtv[13][l2], a0);
      a0 = fmaf(w3.z, dtv[14][l2], a0); a0 = fmaf(w3.w, dtv[15][l2], a0);
      dl_out[((size_t)b * LL + l0 + l2) * DN + dd] = fsoftplus(a0);
    }
  }
}

// ---------------------------------------------------------------------------
// Scan: lane = channel d, 16 states in registers. u/z/y BF16, dl fp32.
// B/C [b][t][n] wave-uniform float4, all streams prefetched 1 step ahead.
// y written in place over u. NC2=128 -> 8 blk/CU.
// ---------------------------------------------------------------------------
#define HSTEP(n, Bcomp, Ccomp)                      \
  {                                                 \
    float e_ = __expf(dc * Av[n]);                  \
    h[n] = fmaf(e_, h[n], dlu * (Bcomp));           \
    if (PHASE == 3) acc = fmaf(h[n], (Ccomp), acc); \
  }

template <int PHASE>
__global__ __launch_bounds__(256) void scan_kernel(
    unsigned short* __restrict__ uy_f, unsigned short* __restrict__ uy_r,
    const float* __restrict__ dl_f, const float* __restrict__ dl_r,
    const unsigned short* __restrict__ z_t, const float* __restrict__ B_f,
    const float* __restrict__ C_f, const float* __restrict__ B_r,
    const float* __restrict__ C_r, const float* __restrict__ A_log,
    const float* __restrict__ Ab_log, const float* __restrict__ D_f,
    const float* __restrict__ D_r, float* __restrict__ hend,
    float* __restrict__ sumdl) {
  const int G2 = 2 * BB * DN;                            // 4096
  const int ch = (blockIdx.x & 15) * 256 + threadIdx.x;  // channel
  const int chunk = blockIdx.x >> 4;                     // 0..NC2-1
  const bool rev = ch >= BB * DN;                        // uniform per block
  const int cid = rev ? ch - BB * DN : ch;
  const int b = cid >> 9;
  const int d = cid & (DN - 1);

  const float* Arow = (rev ? Ab_log : A_log) + d * NS;
  float Av[NS];
#pragma unroll
  for (int n = 0; n < NS; n++) Av[n] = -__expf(Arow[n]);
  const float Dd = (rev ? D_r : D_f)[d];

  unsigned short* uy = (rev ? uy_r : uy_f) + (size_t)b * LL * DN + d;
  const float* dlp = (rev ? dl_r : dl_f) + (size_t)b * LL * DN + d;
  const float* Bp = (rev ? B_r : B_f) + (size_t)b * LL * NS;
  const float* Cp = (rev ? C_r : C_f) + (size_t)b * LL * NS;
  const unsigned short* zp = z_t + (size_t)b * LL * DN + d;

  float h[NS];
  if (PHASE == 3) {
    const float* hp = hend + ((size_t)chunk * G2 + ch) * NS;
#pragma unroll
    for (int n = 0; n < NS; n++) h[n] = hp[n];
  } else {
#pragma unroll
    for (int n = 0; n < NS; n++) h[n] = 0.f;
  }

  const int tstep = rev ? -1 : 1;
  int t = rev ? (LL - 1 - CL2 * chunk) : (CL2 * chunk);
  float sdl = 0.f;
  float uc = bf2f(uy[(size_t)t * DN]);
  float dc = dlp[(size_t)t * DN];
  float zc = (PHASE == 3) ? bf2f(zp[(size_t)t * DN]) : 0.f;
  const float4* Bt4 = (const float4*)(Bp + (size_t)t * NS);
  float4 cB0 = Bt4[0], cB1 = Bt4[1], cB2 = Bt4[2], cB3 = Bt4[3];
  float4 cC0 = {0, 0, 0, 0}, cC1 = {0, 0, 0, 0}, cC2 = {0, 0, 0, 0},
         cC3 = {0, 0, 0, 0};
  if (PHASE == 3) {
    const float4* Ct4 = (const float4*)(Cp + (size_t)t * NS);
    cC0 = Ct4[0]; cC1 = Ct4[1]; cC2 = Ct4[2]; cC3 = Ct4[3];
  }

  for (int s = 0; s < CL2; s++) {
    int tn = t + tstep;
    int tcl = tn < 0 ? 0 : (tn >= LL ? LL - 1 : tn);
    float un = bf2f(uy[(size_t)tcl * DN]);
    float dn_ = dlp[(size_t)tcl * DN];
    float zn = (PHASE == 3) ? bf2f(zp[(size_t)tcl * DN]) : 0.f;
    const float4* Bn4 = (const float4*)(Bp + (size_t)tcl * NS);
    float4 nB0 = Bn4[0], nB1 = Bn4[1], nB2 = Bn4[2], nB3 = Bn4[3];
    float4 nC0 = {0, 0, 0, 0}, nC1 = {0, 0, 0, 0}, nC2 = {0, 0, 0, 0},
           nC3 = {0, 0, 0, 0};
    if (PHASE == 3) {
      const float4* Cn4 = (const float4*)(Cp + (size_t)tcl * NS);
      nC0 = Cn4[0]; nC1 = Cn4[1]; nC2 = Cn4[2]; nC3 = Cn4[3];
    }
    const float dlu = dc * uc;
    float acc = 0.f;
    HSTEP(0, cB0.x, cC0.x)  HSTEP(1, cB0.y, cC0.y)
    HSTEP(2, cB0.z, cC0.z)  HSTEP(3, cB0.w, cC0.w)
    HSTEP(4, cB1.x, cC1.x)  HSTEP(5, cB1.y, cC1.y)
    HSTEP(6, cB1.z, cC1.z)  HSTEP(7, cB1.w, cC1.w)
    HSTEP(8, cB2.x, cC2.x)  HSTEP(9, cB2.y, cC2.y)
    HSTEP(10, cB2.z, cC2.z) HSTEP(11, cB2.w, cC2.w)
    HSTEP(12, cB3.x, cC3.x) HSTEP(13, cB3.y, cC3.y)
    HSTEP(14, cB3.z, cC3.z) HSTEP(15, cB3.w, cC3.w)
    if (PHASE == 1) sdl += dc;
    if (PHASE == 3) {
      float y = fmaf(uc, Dd, acc) * zc;
      uy[(size_t)t * DN] = f2bf(y);
    }
    t = tn; uc = un; dc = dn_; zc = zn;
    cB0 = nB0; cB1 = nB1; cB2 = nB2; cB3 = nB3;
    if (PHASE == 3) { cC0 = nC0; cC1 = nC1; cC2 = nC2; cC3 = nC3; }
  }
  if (PHASE == 1) {
    float* hp = hend + ((size_t)chunk * G2 + ch) * NS;
#pragma unroll
    for (int n = 0; n < NS; n++) hp[n] = h[n];
    sumdl[(size_t)chunk * G2 + ch] = sdl;
  }
}
#undef HSTEP

// ---------------------------------------------------------------------------
// Phase 2 (in-place, LDS-tiled): batch-loaded slabs keep global loads off the
// dependent chain.
// ---------------------------------------------------------------------------
__global__ __launch_bounds__(256) void scan_combine_kernel(
    const float* __restrict__ A_log, const float* __restrict__ Ab_log,
    float* __restrict__ hend, const float* __restrict__ sumdl) {
  const int G2 = 2 * BB * DN;
  __shared__ float tile[8][256];
  __shared__ float sd[8][16];
  const int tid = threadIdx.x;
  const int ch0 = blockIdx.x * 16;
  const int chl = tid >> 4;  // local channel 0..15
  const int n = tid & 15;
  const int ch = ch0 + chl;
  const bool rev = ch >= BB * DN;
  const int d = ch & (DN - 1);
  const float Av = -__expf((rev ? Ab_log : A_log)[d * NS + n]);
  float H = 0.f;
  for (int cb = 0; cb < NC2 / 8; cb++) {
#pragma unroll
    for (int j = 0; j < 8; j++)
      tile[j][tid] = hend[((size_t)(cb * 8 + j) * G2 + ch0) * NS + tid];
    if (tid < 128) {
      int j = tid >> 4, k = tid & 15;
      sd[j][k] = sumdl[(size_t)(cb * 8 + j) * G2 + ch0 + k];
    }
    __syncthreads();
#pragma unroll
    for (int j = 0; j < 8; j++) {
      float tmp = tile[j][tid];
      tile[j][tid] = H;
      H = fmaf(__expf(Av * sd[j][chl]), H, tmp);
    }
    __syncthreads();
#pragma unroll
    for (int j = 0; j < 8; j++)
      hend[((size_t)(cb * 8 + j) * G2 + ch0) * NS + tid] = tile[j][tid];
    __syncthreads();
  }
}

// ---------------------------------------------------------------------------
// out_proj via bf16 MFMA: y now BF16 [b][l][d] -> direct ushort8 loads.
// ---------------------------------------------------------------------------
__global__ __launch_bounds__(256) void out_proj_mfma(
    const unsigned short* __restrict__ yf, const unsigned short* __restrict__ yr,
    const float* __restrict__ ow, float* __restrict__ outp) {
  __shared__ unsigned short yt[64][40];
  __shared__ unsigned short wo[64][40];
  const int b = blockIdx.z;
  const int m0 = blockIdx.y * 64;
  const int l0 = blockIdx.x * 64;
  const int tid = threadIdx.x;
  const int lane = tid & 63;
  const int wid = tid >> 6;
  const int wm = wid >> 1, wn = wid & 1;
  const int krow = (lane >> 4) * 8;
  const int rlo = lane & 15;

  f32x4 acc[2][2];
#pragma unroll
  for (int i = 0; i < 2; i++)
#pragma unroll
    for (int j = 0; j < 2; j++) acc[i][j] = (f32x4){0.f, 0.f, 0.f, 0.f};

  for (int dk = 0; dk < DN; dk += 32) {
    {
      int row = tid >> 2;
      int seg = (tid & 3) * 8;
      ushort8 a = *(const ushort8*)(yf + ((size_t)b * LL + l0 + row) * DN + dk + seg);
      ushort8 c = *(const ushort8*)(yr + ((size_t)b * LL + l0 + row) * DN + dk + seg);
      ushort8 yv;
#pragma unroll
      for (int k = 0; k < 8; k++) yv[k] = f2bf(0.5f * (bf2f(a[k]) + bf2f(c[k])));
      *(ushort8*)&yt[row][seg] = yv;
      const float* wp = ow + (size_t)(m0 + row) * DN + dk + seg;
      float4 w0 = *(const float4*)wp, w1 = *(const float4*)(wp + 4);
      ushort8 wv;
      wv[0] = f2bf(w0.x); wv[1] = f2bf(w0.y); wv[2] = f2bf(w0.z); wv[3] = f2bf(w0.w);
      wv[4] = f2bf(w1.x); wv[5] = f2bf(w1.y); wv[6] = f2bf(w1.z); wv[7] = f2bf(w1.w);
      *(ushort8*)&wo[row][seg] = wv;
    }
    __syncthreads();
    bf16x8 a0 = *(bf16x8*)&yt[wm * 32 + rlo][krow];
    bf16x8 a1 = *(bf16x8*)&yt[wm * 32 + 16 + rlo][krow];
    bf16x8 b0 = *(bf16x8*)&wo[wn * 32 + rlo][krow];
    bf16x8 b1 = *(bf16x8*)&wo[wn * 32 + 16 + rlo][krow];
    acc[0][0] = __builtin_amdgcn_mfma_f32_16x16x32_bf16(a0, b0, acc[0][0], 0, 0, 0);
    acc[0][1] = __builtin_amdgcn_mfma_f32_16x16x32_bf16(a0, b1, acc[0][1], 0, 0, 0);
    acc[1][0] = __builtin_amdgcn_mfma_f32_16x16x32_bf16(a1, b0, acc[1][0], 0, 0, 0);
    acc[1][1] = __builtin_amdgcn_mfma_f32_16x16x32_bf16(a1, b1, acc[1][1], 0, 0, 0);
    __syncthreads();
  }
#pragma unroll
  for (int mt = 0; mt < 2; mt++)
#pragma unroll
    for (int nt = 0; nt < 2; nt++)
#pragma unroll
      for (int r = 0; r < 4; r++) {
        int l = l0 + wm * 32 + mt * 16 + (lane >> 4) * 4 + r;
        int m = m0 + wn * 32 + nt * 16 + rlo;
        outp[((size_t)b * LL + l) * DM + m] = acc[mt][nt][r];
      }
}

// ---------------------------------------------------------------------------
extern "C" void kernel_launch(void* const* d_in, const int* in_sizes, int n_in,
                              void* d_out, int out_size, void* d_ws, size_t ws_size,
                              hipStream_t stream) {
  (void)in_sizes; (void)n_in; (void)out_size; (void)ws_size;
  const float* A_log = (const float*)d_in[2];
  const float* Ab_log = (const float*)d_in[3];

  const size_t SZ = (size_t)BB * LL * DN;      // 4,194,304 elements
  const size_t NSZ = (size_t)BB * LL * NS;     // 131,072
  float* ws = (float*)d_ws;
  float* dl_f = ws;                            // SZ fp32
  float* dl_r = dl_f + SZ;                     // SZ fp32
  float* B_f = dl_r + SZ;                      // NSZ
  float* C_f = B_f + NSZ;
  float* B_r = C_f + NSZ;
  float* C_r = B_r + NSZ;
  float* sumdl = C_r + NSZ;                    // NC2*G2 = 524,288
  unsigned short* xwbf_f = (unsigned short*)(sumdl + (size_t)NC2 * 2 * BB * DN);
  unsigned short* xwbf_r = xwbf_f + 48 * 512;
  unsigned short* z_t = xwbf_r + 48 * 512;     // SZ bf16
  unsigned short* u_f = z_t + SZ;              // SZ bf16 (u -> y in place)
  unsigned short* u_r = u_f + SZ;              // SZ bf16
  float* xz = (float*)(u_r + SZ);              // SZ fp32 (dead after conv)
  float* hend = xz;  // ALIAS: NC2*G2*NS floats (xz region + tail extension)

  for (int s = 0; s < 2; s++) {
    const int p = 4 + s * 14;
    const float* hin = (const float*)d_in[s];
    const float* in_w = (const float*)d_in[p + 0];
    const float* conv_w = (const float*)d_in[p + 1];
    const float* conv_b = (const float*)d_in[p + 2];
    const float* x_w = (const float*)d_in[p + 3];
    const float* dt_w = (const float*)d_in[p + 4];
    const float* dt_b = (const float*)d_in[p + 5];
    const float* Dp = (const float*)d_in[p + 6];
    const float* conv_w_b = (const float*)d_in[p + 7];
    const float* conv_b_b = (const float*)d_in[p + 8];
    const float* x_w_b = (const float*)d_in[p + 9];
    const float* dt_w_b = (const float*)d_in[p + 10];
    const float* dt_b_b = (const float*)d_in[p + 11];
    const float* Dp_b = (const float*)d_in[p + 12];
    const float* out_w = (const float*)d_in[p + 13];
    float* outp = (float*)d_out + (size_t)s * BB * LL * DM;

    hipLaunchKernelGGL(in_proj_mfma, dim3(LL / 128, EE / 128, BB), dim3(256), 0,
                       stream, hin, in_w, xz, z_t);
    hipLaunchKernelGGL(xw_prep_kernel, dim3(96), dim3(256), 0, stream,
                       x_w, x_w_b, xwbf_f, xwbf_r);
    hipLaunchKernelGGL(conv_kernel, dim3((LL / 32) * 4, BB, 2), dim3(256), 0,
                       stream, xz, conv_w, conv_b, conv_w_b, conv_b_b, u_f, u_r);
    hipLaunchKernelGGL(xdbl_kernel, dim3(LL / 16, BB, 2), dim3(256), 0, stream,
                       u_f, u_r, xwbf_f, xwbf_r, dt_w, dt_b, dt_w_b, dt_b_b,
                       dl_f, B_f, C_f, dl_r, B_r, C_r);
    hipLaunchKernelGGL(HIP_KERNEL_NAME(scan_kernel<1>), dim3(NC2 * 16), dim3(256), 0,
                       stream, u_f, u_r, dl_f, dl_r, z_t, B_f, C_f, B_r, C_r, A_log,
                       Ab_log, Dp, Dp_b, hend, sumdl);
    hipLaunchKernelGGL(scan_combine_kernel, dim3(2 * BB * DN / 16), dim3(256),
                       0, stream, A_log, Ab_log, hend, sumdl);
    hipLaunchKernelGGL(HIP_KERNEL_NAME(scan_kernel<3>), dim3(NC2 * 16), dim3(256), 0,
                       stream, u_f, u_r, dl_f, dl_r, z_t, B_f, C_f, B_r, C_r, A_log,
                       Ab_log, Dp, Dp_b, hend, sumdl);
    hipLaunchKernelGGL(out_proj_mfma, dim3(LL / 64, DM / 64, BB), dim3(256), 0,
                       stream, u_f, u_r, out_w, outp);
  }
}

// Round 16
// 360.057 us; speedup vs baseline: 1.2777x; 1.1226x over previous
//
#include <hip/hip_runtime.h>
#include <hip/hip_bf16.h>
#include <cstddef>

#define BB 4
#define LL 2048
#define DM 256
#define DN 512
#define EE 1024
#define NS 16
#define RK 16
#define NC2 128         // scan chunks
#define CL2 (LL / NC2)  // chunk length = 16

typedef __attribute__((ext_vector_type(8))) short bf16x8;
typedef __attribute__((ext_vector_type(8))) unsigned short ushort8;
typedef __attribute__((ext_vector_type(4))) unsigned short ushort4v;
typedef __attribute__((ext_vector_type(2))) unsigned short ushort2v;
typedef __attribute__((ext_vector_type(4))) float f32x4;

__device__ __forceinline__ float fsilu(float x) { return x / (1.0f + __expf(-x)); }
__device__ __forceinline__ float fsoftplus(float x) { return x > 20.0f ? x : log1pf(__expf(x)); }
__device__ __forceinline__ unsigned short f2bf(float x) {  // RNE float->bf16
  union { float f; unsigned int u; } v; v.f = x;
  unsigned int r = v.u + 0x7fffu + ((v.u >> 16) & 1u);
  return (unsigned short)(r >> 16);
}
__device__ __forceinline__ float bf2f(unsigned short x) {
  union { unsigned int u; float f; } v; v.u = ((unsigned int)x) << 16;
  return v.f;
}

// ---------------------------------------------------------------------------
// in_proj via bf16 MFMA. x-blocks (e<DN): C[e][l] -> xz[b][e][l] fp32.
// z-blocks: swap A/B so C[l][d] -> z_t[b][l][d] = silu, stored BF16.
// ---------------------------------------------------------------------------
__global__ __launch_bounds__(256) void in_proj_mfma(
    const float* __restrict__ h, const float* __restrict__ w,
    float* __restrict__ xz, unsigned short* __restrict__ z_t) {
  __shared__ unsigned short ht[128][40];  // [l][k] bf16
  __shared__ unsigned short wt[128][40];  // [e][k]
  const int b = blockIdx.z;
  const int e0 = blockIdx.y * 128;
  const int l0 = blockIdx.x * 128;
  const int tid = threadIdx.x;
  const int lane = tid & 63;
  const int wid = tid >> 6;
  const int wm = wid >> 1, wn = wid & 1;
  const bool zblk = (e0 >= DN);
  const int krow = (lane >> 4) * 8;
  const int rlo = lane & 15;

  f32x4 acc[4][4];
#pragma unroll
  for (int i = 0; i < 4; i++)
#pragma unroll
    for (int j = 0; j < 4; j++) acc[i][j] = (f32x4){0.f, 0.f, 0.f, 0.f};

  for (int dk = 0; dk < DM; dk += 32) {
#pragma unroll
    for (int it = 0; it < 2; it++) {
      int idx = it * 256 + tid;
      int row = idx >> 2;
      int seg = (idx & 3) * 8;
      const float* hp = h + ((size_t)b * LL + l0 + row) * DM + dk + seg;
      float4 ha = *(const float4*)hp, hb = *(const float4*)(hp + 4);
      ushort8 hv;
      hv[0] = f2bf(ha.x); hv[1] = f2bf(ha.y); hv[2] = f2bf(ha.z); hv[3] = f2bf(ha.w);
      hv[4] = f2bf(hb.x); hv[5] = f2bf(hb.y); hv[6] = f2bf(hb.z); hv[7] = f2bf(hb.w);
      *(ushort8*)&ht[row][seg] = hv;
      const float* wp = w + (size_t)(e0 + row) * DM + dk + seg;
      float4 wa = *(const float4*)wp, wb = *(const float4*)(wp + 4);
      ushort8 wv;
      wv[0] = f2bf(wa.x); wv[1] = f2bf(wa.y); wv[2] = f2bf(wa.z); wv[3] = f2bf(wa.w);
      wv[4] = f2bf(wb.x); wv[5] = f2bf(wb.y); wv[6] = f2bf(wb.z); wv[7] = f2bf(wb.w);
      *(ushort8*)&wt[row][seg] = wv;
    }
    __syncthreads();
    unsigned short (*Ab)[40] = zblk ? ht : wt;
    unsigned short (*Bb)[40] = zblk ? wt : ht;
    bf16x8 af[4], bfr[4];
#pragma unroll
    for (int mt = 0; mt < 4; mt++)
      af[mt] = *(bf16x8*)&Ab[wm * 64 + mt * 16 + rlo][krow];
#pragma unroll
    for (int nt = 0; nt < 4; nt++)
      bfr[nt] = *(bf16x8*)&Bb[wn * 64 + nt * 16 + rlo][krow];
#pragma unroll
    for (int mt = 0; mt < 4; mt++)
#pragma unroll
      for (int nt = 0; nt < 4; nt++)
        acc[mt][nt] = __builtin_amdgcn_mfma_f32_16x16x32_bf16(
            af[mt], bfr[nt], acc[mt][nt], 0, 0, 0);
    __syncthreads();
  }
  if (!zblk) {
#pragma unroll
    for (int mt = 0; mt < 4; mt++)
#pragma unroll
      for (int nt = 0; nt < 4; nt++)
#pragma unroll
        for (int r = 0; r < 4; r++) {
          int e = e0 + wm * 64 + mt * 16 + (lane >> 4) * 4 + r;
          int l = l0 + wn * 64 + nt * 16 + rlo;
          xz[((size_t)b * DN + e) * LL + l] = acc[mt][nt][r];
        }
  } else {
#pragma unroll
    for (int mt = 0; mt < 4; mt++)
#pragma unroll
      for (int nt = 0; nt < 4; nt++)
#pragma unroll
        for (int r = 0; r < 4; r++) {
          int l = l0 + wm * 64 + mt * 16 + (lane >> 4) * 4 + r;
          int d = (e0 - DN) + wn * 64 + nt * 16 + rlo;
          z_t[((size_t)b * LL + l) * DN + d] = f2bf(fsilu(acc[mt][nt][r]));
        }
  }
}

// ---------------------------------------------------------------------------
// conv_kernel: streaming conv+silu+transpose. Writes u[b][l][d] as BF16.
// ---------------------------------------------------------------------------
__global__ __launch_bounds__(256) void conv_kernel(
    const float* __restrict__ xz,
    const float* __restrict__ cw_f, const float* __restrict__ cb_f,
    const float* __restrict__ cw_r, const float* __restrict__ cb_r,
    unsigned short* __restrict__ u_f, unsigned short* __restrict__ u_r) {
  __shared__ float xt[128][33];
  const int rev = blockIdx.z;
  const int b = blockIdx.y;
  const int dc0 = (blockIdx.x & 3) * 128;
  const int l0 = (blockIdx.x >> 2) * 32;
  const int tid = threadIdx.x;
  const int lc = tid & 31;
  const int dg = tid >> 5;  // 0..7
  const int l = l0 + lc;
  const float* conv_w = rev ? cw_r : cw_f;
  const float* conv_b = rev ? cb_r : cb_f;
  unsigned short* u_out = rev ? u_r : u_f;

#pragma unroll
  for (int i = 0; i < 16; i++) {
    int dloc = dg * 16 + i;
    int dd = dc0 + dloc;
    const float* base = xz + ((size_t)b * DN + dd) * LL;
    float4 cw4 = *(const float4*)(conv_w + dd * 4);
    float a0 = conv_b[dd];
    if (rev) {
      a0 = fmaf(cw4.w, base[l], a0);
      if (l + 1 < LL) a0 = fmaf(cw4.z, base[l + 1], a0);
      if (l + 2 < LL) a0 = fmaf(cw4.y, base[l + 2], a0);
      if (l + 3 < LL) a0 = fmaf(cw4.x, base[l + 3], a0);
    } else {
      a0 = fmaf(cw4.w, base[l], a0);
      if (l - 1 >= 0) a0 = fmaf(cw4.z, base[l - 1], a0);
      if (l - 2 >= 0) a0 = fmaf(cw4.y, base[l - 2], a0);
      if (l - 3 >= 0) a0 = fmaf(cw4.x, base[l - 3], a0);
    }
    xt[dloc][lc] = fsilu(a0);
  }
  __syncthreads();
#pragma unroll
  for (int j = 0; j < 8; j++) {
    int idx = j * 256 + tid;  // 0..2047 ushort2 units
    int d2 = idx & 63;        // ushort2 column (d = 2*d2)
    int l2 = idx >> 6;        // 0..31
    ushort2v v;
    v[0] = f2bf(xt[2 * d2][l2]);
    v[1] = f2bf(xt[2 * d2 + 1][l2]);
    *(ushort2v*)&u_out[((size_t)b * LL + l0 + l2) * DN + dc0 + 2 * d2] = v;
  }
}

// ---------------------------------------------------------------------------
// prep: convert x_w (48x512 fp32) of both branches to bf16 global.
// ---------------------------------------------------------------------------
__global__ __launch_bounds__(256) void xw_prep_kernel(
    const float* __restrict__ xw_f, const float* __restrict__ xw_r,
    unsigned short* __restrict__ o_f, unsigned short* __restrict__ o_r) {
  int i = blockIdx.x * 256 + threadIdx.x;
  if (i < 48 * 512) {
    o_f[i] = f2bf(xw_f[i]);
    o_r[i] = f2bf(xw_r[i]);
  }
}

// ---------------------------------------------------------------------------
// xdbl_kernel: x_dbl GEMM (48 x 16l x 512) + fused delta. u BF16 -> staging
// is a straight ushort8 copy.
// ---------------------------------------------------------------------------
__global__ __launch_bounds__(256) void xdbl_kernel(
    const unsigned short* __restrict__ u_f, const unsigned short* __restrict__ u_r,
    const unsigned short* __restrict__ xwb_f,
    const unsigned short* __restrict__ xwb_r,
    const float* __restrict__ dtw_f, const float* __restrict__ dtb_f,
    const float* __restrict__ dtw_r, const float* __restrict__ dtb_r,
    float* __restrict__ dl_f, float* __restrict__ B_f, float* __restrict__ C_f,
    float* __restrict__ dl_r, float* __restrict__ B_r, float* __restrict__ C_r) {
  __shared__ __align__(16) unsigned short ub[4][16][136];  // u tile, per k-chunk
  __shared__ float red[4][48][17];                         // per-wave partials
  __shared__ float dtv[16][17];                            // dt rows
  const int rev = blockIdx.z;
  const int b = blockIdx.y;
  const int l0 = blockIdx.x * 16;
  const int tid = threadIdx.x;
  const int lane = tid & 63;
  const int w = tid >> 6;  // wave = k-chunk 0..3
  const int rlo = lane & 15;
  const int hi4 = lane >> 4;  // 0..3
  const int kseg = hi4 * 8;

  const unsigned short* up = (rev ? u_r : u_f) + ((size_t)b * LL + l0) * DN;
  const unsigned short* xwb = rev ? xwb_r : xwb_f;
  const float* dt_w = rev ? dtw_r : dtw_f;
  const float* dt_b = rev ? dtb_r : dtb_f;
  float* dl_out = rev ? dl_r : dl_f;
  float* B_out = rev ? B_r : B_f;
  float* C_out = rev ? C_r : C_f;

#pragma unroll
  for (int j = 0; j < 4; j++) {
    int idx = j * 256 + tid;  // 0..1023 ushort8 units
    int l2 = idx >> 6;        // 0..15
    int c8 = idx & 63;        // ushort8 col
    ushort8 v = *(const ushort8*)(up + (size_t)l2 * DN + c8 * 8);
    *(ushort8*)&ub[c8 >> 4][l2][(c8 & 15) * 8] = v;
  }
  __syncthreads();

  f32x4 am0 = (f32x4){0.f, 0.f, 0.f, 0.f};
  f32x4 am1 = (f32x4){0.f, 0.f, 0.f, 0.f};
  f32x4 am2 = (f32x4){0.f, 0.f, 0.f, 0.f};
#pragma unroll
  for (int ks = 0; ks < 4; ks++) {
    bf16x8 bfrag = *(bf16x8*)&ub[w][rlo][ks * 32 + kseg];
    const unsigned short* xp = xwb + (size_t)(w * 128 + ks * 32 + kseg);
    bf16x8 a0 = *(const bf16x8*)(xp + (size_t)(0 + rlo) * 512);
    bf16x8 a1 = *(const bf16x8*)(xp + (size_t)(16 + rlo) * 512);
    bf16x8 a2 = *(const bf16x8*)(xp + (size_t)(32 + rlo) * 512);
    am0 = __builtin_amdgcn_mfma_f32_16x16x32_bf16(a0, bfrag, am0, 0, 0, 0);
    am1 = __builtin_amdgcn_mfma_f32_16x16x32_bf16(a1, bfrag, am1, 0, 0, 0);
    am2 = __builtin_amdgcn_mfma_f32_16x16x32_bf16(a2, bfrag, am2, 0, 0, 0);
  }
  {
    const int rbase = hi4 * 4;
#pragma unroll
    for (int r = 0; r < 4; r++) red[w][0 + rbase + r][rlo] = am0[r];
#pragma unroll
    for (int r = 0; r < 4; r++) red[w][16 + rbase + r][rlo] = am1[r];
#pragma unroll
    for (int r = 0; r < 4; r++) red[w][32 + rbase + r][rlo] = am2[r];
  }
  __syncthreads();
#pragma unroll
  for (int i = 0; i < 3; i++) {
    int o = i * 256 + tid;  // 0..767
    int row = o >> 4, col = o & 15;
    float s = (red[0][row][col] + red[1][row][col]) +
              (red[2][row][col] + red[3][row][col]);
    if (row < 16)
      dtv[row][col] = s;
    else if (row < 32)
      B_out[((size_t)b * LL + l0 + col) * NS + (row - 16)] = s;
    else
      C_out[((size_t)b * LL + l0 + col) * NS + (row - 32)] = s;
  }
  __syncthreads();
#pragma unroll
  for (int half = 0; half < 2; half++) {
    int dd = half * 256 + tid;
    const float4* wr = (const float4*)(dt_w + (size_t)dd * RK);
    float4 w0 = wr[0], w1 = wr[1], w2 = wr[2], w3 = wr[3];
    float bias = dt_b[dd];
#pragma unroll
    for (int l2 = 0; l2 < 16; l2++) {
      float a0 = bias;
      a0 = fmaf(w0.x, dtv[0][l2], a0);  a0 = fmaf(w0.y, dtv[1][l2], a0);
      a0 = fmaf(w0.z, dtv[2][l2], a0);  a0 = fmaf(w0.w, dtv[3][l2], a0);
      a0 = fmaf(w1.x, dtv[4][l2], a0);  a0 = fmaf(w1.y, dtv[5][l2], a0);
      a0 = fmaf(w1.z, dtv[6][l2], a0);  a0 = fmaf(w1.w, dtv[7][l2], a0);
      a0 = fmaf(w2.x, dtv[8][l2], a0);  a0 = fmaf(w2.y, dtv[9][l2], a0);
      a0 = fmaf(w2.z, dtv[10][l2], a0); a0 = fmaf(w2.w, dtv[11][l2], a0);
      a0 = fmaf(w3.x, dtv[12][l2], a0); a0 = fmaf(w3.y, dtv[13][l2], a0);
      a0 = fmaf(w3.z, dtv[14][l2], a0); a0 = fmaf(w3.w, dtv[15][l2], a0);
      dl_out[((size_t)b * LL + l0 + l2) * DN + dd] = fsoftplus(a0);
    }
  }
}

// ---------------------------------------------------------------------------
// Scan (LDS-staged): block = 256 channels x 1 chunk (uniform b/rev). Stage
// the ENTIRE chunk tile (u/dl/z rows + B/C) with independent coalesced loads
// (one latency exposure), then run the 16-step recurrence from LDS.
// u/z/y BF16, dl fp32. y written in place over u (per-thread column +tid!).
// ---------------------------------------------------------------------------
#define HSTEP(n, Bcomp, Ccomp)                      \
  {                                                 \
    float e_ = __expf(dc * Av[n]);                  \
    h[n] = fmaf(e_, h[n], dlu * (Bcomp));           \
    if (PHASE == 3) acc = fmaf(h[n], (Ccomp), acc); \
  }

template <int PHASE>
__global__ __launch_bounds__(256) void scan_kernel(
    unsigned short* __restrict__ uy_f, unsigned short* __restrict__ uy_r,
    const float* __restrict__ dl_f, const float* __restrict__ dl_r,
    const unsigned short* __restrict__ z_t, const float* __restrict__ B_f,
    const float* __restrict__ C_f, const float* __restrict__ B_r,
    const float* __restrict__ C_r, const float* __restrict__ A_log,
    const float* __restrict__ Ab_log, const float* __restrict__ D_f,
    const float* __restrict__ D_r, float* __restrict__ hend,
    float* __restrict__ sumdl) {
  __shared__ unsigned short us[CL2][256];  // 8 KB
  __shared__ unsigned short zs[CL2][256];  // 8 KB
  __shared__ float dls[CL2][256];          // 16 KB
  __shared__ float Bs[CL2][16];            // 1 KB
  __shared__ float Cs[CL2][16];            // 1 KB
  const int G2 = 2 * BB * DN;              // 4096
  const int tid = threadIdx.x;
  const int ch0 = (blockIdx.x & 15) * 256;
  const int chunk = blockIdx.x >> 4;  // 0..NC2-1
  const int ch = ch0 + tid;
  const bool rev = ch0 >= BB * DN;  // uniform per block
  const int cid0 = rev ? ch0 - BB * DN : ch0;
  const int b = cid0 >> 9;
  const int d0 = cid0 & (DN - 1);  // thread's d = d0 + tid
  const int d = d0 + tid;

  const float* Arow = (rev ? Ab_log : A_log) + d * NS;
  float Av[NS];
#pragma unroll
  for (int n = 0; n < NS; n++) Av[n] = -__expf(Arow[n]);
  const float Dd = (rev ? D_r : D_f)[d];

  const int tlo = rev ? (LL - CL2 * (chunk + 1)) : (CL2 * chunk);
  unsigned short* uyb = (rev ? uy_r : uy_f) + ((size_t)b * LL + tlo) * DN + d0;
  const float* dlb = (rev ? dl_r : dl_f) + ((size_t)b * LL + tlo) * DN + d0;
  const unsigned short* zb = z_t + ((size_t)b * LL + tlo) * DN + d0;
  const float* Bp = (rev ? B_r : B_f) + ((size_t)b * LL + tlo) * NS;
  const float* Cp = (rev ? C_r : C_f) + ((size_t)b * LL + tlo) * NS;

  // ---- stage the whole chunk tile: all loads independent, all in flight ----
  {
    const int lane = tid & 63;
    const int w = tid >> 6;  // wave stages rows w*4..w*4+3
#pragma unroll
    for (int j4 = 0; j4 < 4; j4++) {
      int row = w * 4 + j4;
      ushort4v uu = *(const ushort4v*)(uyb + (size_t)row * DN + lane * 4);
      *(ushort4v*)&us[row][lane * 4] = uu;
      float4 dd4 = *(const float4*)(dlb + (size_t)row * DN + lane * 4);
      *(float4*)&dls[row][lane * 4] = dd4;
      if (PHASE == 3) {
        ushort4v zz = *(const ushort4v*)(zb + (size_t)row * DN + lane * 4);
        *(ushort4v*)&zs[row][lane * 4] = zz;
      }
    }
    // B/C: 16 rows x 16 floats
    Bs[tid >> 4][tid & 15] = Bp[(size_t)(tid >> 4) * NS + (tid & 15)];
    if (PHASE == 3) Cs[tid >> 4][tid & 15] = Cp[(size_t)(tid >> 4) * NS + (tid & 15)];
  }

  float h[NS];
  if (PHASE == 3) {
    const float* hp = hend + ((size_t)chunk * G2 + ch) * NS;
#pragma unroll
    for (int n = 0; n < NS; n++) h[n] = hp[n];
  } else {
#pragma unroll
    for (int n = 0; n < NS; n++) h[n] = 0.f;
  }
  __syncthreads();

  float sdl = 0.f;
#pragma unroll
  for (int jj = 0; jj < CL2; jj++) {
    const int j = rev ? (CL2 - 1 - jj) : jj;  // LDS index (runtime ok)
    const float uc = bf2f(us[j][tid]);
    const float dc = dls[j][tid];
    const float4 Bq0 = *(const float4*)&Bs[j][0];
    const float4 Bq1 = *(const float4*)&Bs[j][4];
    const float4 Bq2 = *(const float4*)&Bs[j][8];
    const float4 Bq3 = *(const float4*)&Bs[j][12];
    float4 Cq0 = {0, 0, 0, 0}, Cq1 = {0, 0, 0, 0}, Cq2 = {0, 0, 0, 0},
           Cq3 = {0, 0, 0, 0};
    if (PHASE == 3) {
      Cq0 = *(const float4*)&Cs[j][0];
      Cq1 = *(const float4*)&Cs[j][4];
      Cq2 = *(const float4*)&Cs[j][8];
      Cq3 = *(const float4*)&Cs[j][12];
    }
    const float dlu = dc * uc;
    float acc = 0.f;
    HSTEP(0, Bq0.x, Cq0.x)  HSTEP(1, Bq0.y, Cq0.y)
    HSTEP(2, Bq0.z, Cq0.z)  HSTEP(3, Bq0.w, Cq0.w)
    HSTEP(4, Bq1.x, Cq1.x)  HSTEP(5, Bq1.y, Cq1.y)
    HSTEP(6, Bq1.z, Cq1.z)  HSTEP(7, Bq1.w, Cq1.w)
    HSTEP(8, Bq2.x, Cq2.x)  HSTEP(9, Bq2.y, Cq2.y)
    HSTEP(10, Bq2.z, Cq2.z) HSTEP(11, Bq2.w, Cq2.w)
    HSTEP(12, Bq3.x, Cq3.x) HSTEP(13, Bq3.y, Cq3.y)
    HSTEP(14, Bq3.z, Cq3.z) HSTEP(15, Bq3.w, Cq3.w)
    if (PHASE == 1) sdl += dc;
    if (PHASE == 3) {
      const float zc = bf2f(zs[j][tid]);
      float y = fmaf(uc, Dd, acc) * zc;
      uyb[(size_t)j * DN + tid] = f2bf(y);  // FIX: per-thread column (+tid)
    }
  }
  if (PHASE == 1) {
    float* hp = hend + ((size_t)chunk * G2 + ch) * NS;
#pragma unroll
    for (int n = 0; n < NS; n++) hp[n] = h[n];
    sumdl[(size_t)chunk * G2 + ch] = sdl;
  }
}
#undef HSTEP

// ---------------------------------------------------------------------------
// Phase 2 (in-place, LDS-tiled): batch-loaded slabs keep global loads off the
// dependent chain.
// ---------------------------------------------------------------------------
__global__ __launch_bounds__(256) void scan_combine_kernel(
    const float* __restrict__ A_log, const float* __restrict__ Ab_log,
    float* __restrict__ hend, const float* __restrict__ sumdl) {
  const int G2 = 2 * BB * DN;
  __shared__ float tile[8][256];
  __shared__ float sd[8][16];
  const int tid = threadIdx.x;
  const int ch0 = blockIdx.x * 16;
  const int chl = tid >> 4;  // local channel 0..15
  const int n = tid & 15;
  const int ch = ch0 + chl;
  const bool rev = ch >= BB * DN;
  const int d = ch & (DN - 1);
  const float Av = -__expf((rev ? Ab_log : A_log)[d * NS + n]);
  float H = 0.f;
  for (int cb = 0; cb < NC2 / 8; cb++) {
#pragma unroll
    for (int j = 0; j < 8; j++)
      tile[j][tid] = hend[((size_t)(cb * 8 + j) * G2 + ch0) * NS + tid];
    if (tid < 128) {
      int j = tid >> 4, k = tid & 15;
      sd[j][k] = sumdl[(size_t)(cb * 8 + j) * G2 + ch0 + k];
    }
    __syncthreads();
#pragma unroll
    for (int j = 0; j < 8; j++) {
      float tmp = tile[j][tid];
      tile[j][tid] = H;
      H = fmaf(__expf(Av * sd[j][chl]), H, tmp);
    }
    __syncthreads();
#pragma unroll
    for (int j = 0; j < 8; j++)
      hend[((size_t)(cb * 8 + j) * G2 + ch0) * NS + tid] = tile[j][tid];
    __syncthreads();
  }
}

// ---------------------------------------------------------------------------
// out_proj via bf16 MFMA: y BF16 [b][l][d] -> direct ushort8 loads.
// ---------------------------------------------------------------------------
__global__ __launch_bounds__(256) void out_proj_mfma(
    const unsigned short* __restrict__ yf, const unsigned short* __restrict__ yr,
    const float* __restrict__ ow, float* __restrict__ outp) {
  __shared__ unsigned short yt[64][40];
  __shared__ unsigned short wo[64][40];
  const int b = blockIdx.z;
  const int m0 = blockIdx.y * 64;
  const int l0 = blockIdx.x * 64;
  const int tid = threadIdx.x;
  const int lane = tid & 63;
  const int wid = tid >> 6;
  const int wm = wid >> 1, wn = wid & 1;
  const int krow = (lane >> 4) * 8;
  const int rlo = lane & 15;

  f32x4 acc[2][2];
#pragma unroll
  for (int i = 0; i < 2; i++)
#pragma unroll
    for (int j = 0; j < 2; j++) acc[i][j] = (f32x4){0.f, 0.f, 0.f, 0.f};

  for (int dk = 0; dk < DN; dk += 32) {
    {
      int row = tid >> 2;
      int seg = (tid & 3) * 8;
      ushort8 a = *(const ushort8*)(yf + ((size_t)b * LL + l0 + row) * DN + dk + seg);
      ushort8 c = *(const ushort8*)(yr + ((size_t)b * LL + l0 + row) * DN + dk + seg);
      ushort8 yv;
#pragma unroll
      for (int k = 0; k < 8; k++) yv[k] = f2bf(0.5f * (bf2f(a[k]) + bf2f(c[k])));
      *(ushort8*)&yt[row][seg] = yv;
      const float* wp = ow + (size_t)(m0 + row) * DN + dk + seg;
      float4 w0 = *(const float4*)wp, w1 = *(const float4*)(wp + 4);
      ushort8 wv;
      wv[0] = f2bf(w0.x); wv[1] = f2bf(w0.y); wv[2] = f2bf(w0.z); wv[3] = f2bf(w0.w);
      wv[4] = f2bf(w1.x); wv[5] = f2bf(w1.y); wv[6] = f2bf(w1.z); wv[7] = f2bf(w1.w);
      *(ushort8*)&wo[row][seg] = wv;
    }
    __syncthreads();
    bf16x8 a0 = *(bf16x8*)&yt[wm * 32 + rlo][krow];
    bf16x8 a1 = *(bf16x8*)&yt[wm * 32 + 16 + rlo][krow];
    bf16x8 b0 = *(bf16x8*)&wo[wn * 32 + rlo][krow];
    bf16x8 b1 = *(bf16x8*)&wo[wn * 32 + 16 + rlo][krow];
    acc[0][0] = __builtin_amdgcn_mfma_f32_16x16x32_bf16(a0, b0, acc[0][0], 0, 0, 0);
    acc[0][1] = __builtin_amdgcn_mfma_f32_16x16x32_bf16(a0, b1, acc[0][1], 0, 0, 0);
    acc[1][0] = __builtin_amdgcn_mfma_f32_16x16x32_bf16(a1, b0, acc[1][0], 0, 0, 0);
    acc[1][1] = __builtin_amdgcn_mfma_f32_16x16x32_bf16(a1, b1, acc[1][1], 0, 0, 0);
    __syncthreads();
  }
#pragma unroll
  for (int mt = 0; mt < 2; mt++)
#pragma unroll
    for (int nt = 0; nt < 2; nt++)
#pragma unroll
      for (int r = 0; r < 4; r++) {
        int l = l0 + wm * 32 + mt * 16 + (lane >> 4) * 4 + r;
        int m = m0 + wn * 32 + nt * 16 + rlo;
        outp[((size_t)b * LL + l) * DM + m] = acc[mt][nt][r];
      }
}

// ---------------------------------------------------------------------------
extern "C" void kernel_launch(void* const* d_in, const int* in_sizes, int n_in,
                              void* d_out, int out_size, void* d_ws, size_t ws_size,
                              hipStream_t stream) {
  (void)in_sizes; (void)n_in; (void)out_size; (void)ws_size;
  const float* A_log = (const float*)d_in[2];
  const float* Ab_log = (const float*)d_in[3];

  const size_t SZ = (size_t)BB * LL * DN;      // 4,194,304 elements
  const size_t NSZ = (size_t)BB * LL * NS;     // 131,072
  float* ws = (float*)d_ws;
  float* dl_f = ws;                            // SZ fp32
  float* dl_r = dl_f + SZ;                     // SZ fp32
  float* B_f = dl_r + SZ;                      // NSZ
  float* C_f = B_f + NSZ;
  float* B_r = C_f + NSZ;
  float* C_r = B_r + NSZ;
  float* sumdl = C_r + NSZ;                    // NC2*G2 = 524,288
  unsigned short* xwbf_f = (unsigned short*)(sumdl + (size_t)NC2 * 2 * BB * DN);
  unsigned short* xwbf_r = xwbf_f + 48 * 512;
  unsigned short* z_t = xwbf_r + 48 * 512;     // SZ bf16
  unsigned short* u_f = z_t + SZ;              // SZ bf16 (u -> y in place)
  unsigned short* u_r = u_f + SZ;              // SZ bf16
  float* xz = (float*)(u_r + SZ);              // SZ fp32 (dead after conv)
  float* hend = xz;  // ALIAS: NC2*G2*NS floats (xz region + tail extension)

  for (int s = 0; s < 2; s++) {
    const int p = 4 + s * 14;
    const float* hin = (const float*)d_in[s];
    const float* in_w = (const float*)d_in[p + 0];
    const float* conv_w = (const float*)d_in[p + 1];
    const float* conv_b = (const float*)d_in[p + 2];
    const float* x_w = (const float*)d_in[p + 3];
    const float* dt_w = (const float*)d_in[p + 4];
    const float* dt_b = (const float*)d_in[p + 5];
    const float* Dp = (const float*)d_in[p + 6];
    const float* conv_w_b = (const float*)d_in[p + 7];
    const float* conv_b_b = (const float*)d_in[p + 8];
    const float* x_w_b = (const float*)d_in[p + 9];
    const float* dt_w_b = (const float*)d_in[p + 10];
    const float* dt_b_b = (const float*)d_in[p + 11];
    const float* Dp_b = (const float*)d_in[p + 12];
    const float* out_w = (const float*)d_in[p + 13];
    float* outp = (float*)d_out + (size_t)s * BB * LL * DM;

    hipLaunchKernelGGL(in_proj_mfma, dim3(LL / 128, EE / 128, BB), dim3(256), 0,
                       stream, hin, in_w, xz, z_t);
    hipLaunchKernelGGL(xw_prep_kernel, dim3(96), dim3(256), 0, stream,
                       x_w, x_w_b, xwbf_f, xwbf_r);
    hipLaunchKernelGGL(conv_kernel, dim3((LL / 32) * 4, BB, 2), dim3(256), 0,
                       stream, xz, conv_w, conv_b, conv_w_b, conv_b_b, u_f, u_r);
    hipLaunchKernelGGL(xdbl_kernel, dim3(LL / 16, BB, 2), dim3(256), 0, stream,
                       u_f, u_r, xwbf_f, xwbf_r, dt_w, dt_b, dt_w_b, dt_b_b,
                       dl_f, B_f, C_f, dl_r, B_r, C_r);
    hipLaunchKernelGGL(HIP_KERNEL_NAME(scan_kernel<1>), dim3(NC2 * 16), dim3(256), 0,
                       stream, u_f, u_r, dl_f, dl_r, z_t, B_f, C_f, B_r, C_r, A_log,
                       Ab_log, Dp, Dp_b, hend, sumdl);
    hipLaunchKernelGGL(scan_combine_kernel, dim3(2 * BB * DN / 16), dim3(256),
                       0, stream, A_log, Ab_log, hend, sumdl);
    hipLaunchKernelGGL(HIP_KERNEL_NAME(scan_kernel<3>), dim3(NC2 * 16), dim3(256), 0,
                       stream, u_f, u_r, dl_f, dl_r, z_t, B_f, C_f, B_r, C_r, A_log,
                       Ab_log, Dp, Dp_b, hend, sumdl);
    hipLaunchKernelGGL(out_proj_mfma, dim3(LL / 64, DM / 64, BB), dim3(256), 0,
                       stream, u_f, u_r, out_w, outp);
  }
}